// Round 1
// baseline (404.967 us; speedup 1.0000x reference)
//
#include <hip/hip_runtime.h>

#define B_ 64
#define CIN 64
#define T_ 2048
#define C1 16
#define T1 1024
#define C2 32
#define T2 512
#define NN 32768
#define HID 256
#define OUTD 10
#define NE 524288
#define NTOT (NE + NN)

typedef __attribute__((ext_vector_type(4))) float fx4;

// ---- workspace byte offsets (total ~75.3 MB) ----
#define OFF_A      (0ull)                    // 32 MB: h1 (4MB) then xw
#define OFF_B      (32ull<<20)               // 32 MB: h / out
#define OFF_XN     (64ull<<20)               // 4 MB: node features [N][32]
#define OFF_DEG    (68ull<<20)               // 128 KB int
#define OFF_INDPTR ((68ull<<20) + (256u<<10))
#define OFF_CNT    ((68ull<<20) + (512u<<10))
#define OFF_DINV   ((68ull<<20) + (768u<<10))
#define OFF_CSRC   (69ull<<20)               // (E+N)*4 = 2.125 MB
#define OFF_CNORM  (72ull<<20)               // 2.125 MB
#define OFF_WT1    (75ull<<20)               // 20 KB
#define OFF_WT2    ((75ull<<20) + (64u<<10)) // 10 KB
#define OFF_POOL   ((75ull<<20) + (128u<<10))// 64 KB

__global__ __launch_bounds__(256) void k_init(int* deg, int* cnt, float* pooled) {
    int i = blockIdx.x * 256 + threadIdx.x;
    if (i < NN) { deg[i] = 1; cnt[i] = 0; }       // deg starts at 1 (self-loop)
    if (i < B_ * HID) pooled[i] = 0.f;
}

__global__ __launch_bounds__(256) void k_count(const int* __restrict__ ei, int* __restrict__ deg) {
    int e = blockIdx.x * 256 + threadIdx.x;
    if (e < NE) atomicAdd(&deg[ei[NE + e]], 1);
}

__global__ __launch_bounds__(256) void k_dinv(const int* __restrict__ deg, float* __restrict__ dinv) {
    int i = blockIdx.x * 256 + threadIdx.x;
    if (i < NN) dinv[i] = rsqrtf((float)deg[i]);
}

__global__ __launch_bounds__(1024) void k_scan(const int* __restrict__ deg, int* __restrict__ indptr) {
    __shared__ int sd[1024];
    int tid = threadIdx.x;
    int base = tid * 32;
    int loc[32]; int s = 0;
    #pragma unroll
    for (int j = 0; j < 32; j++) { loc[j] = deg[base + j]; s += loc[j]; }
    sd[tid] = s; __syncthreads();
    for (int off = 1; off < 1024; off <<= 1) {
        int v = (tid >= off) ? sd[tid - off] : 0;
        __syncthreads();
        if (tid >= off) sd[tid] += v;
        __syncthreads();
    }
    int run = sd[tid] - s;
    #pragma unroll
    for (int j = 0; j < 32; j++) { indptr[base + j] = run; run += loc[j]; }
    if (tid == 1023) indptr[NN] = run;
}

__global__ __launch_bounds__(256) void k_fill(const int* __restrict__ ei, const float* __restrict__ dinv,
                                              const int* __restrict__ indptr, int* __restrict__ cnt,
                                              int* __restrict__ csrc, float* __restrict__ cnorm) {
    int e = blockIdx.x * 256 + threadIdx.x;
    if (e >= NTOT) return;
    int s, d; float nrm;
    if (e < NE) { s = ei[e]; d = ei[NE + e]; nrm = dinv[s] * dinv[d]; }
    else        { s = d = e - NE;            nrm = dinv[s] * dinv[s]; }
    int pos = indptr[d] + atomicAdd(&cnt[d], 1);
    csrc[pos] = s; cnorm[pos] = nrm;
}

// transpose conv weights -> [ci][k][co] so inner loads are wave-uniform (scalar/L1 broadcast)
__global__ __launch_bounds__(256) void k_twt(const float* __restrict__ w1, const float* __restrict__ w2,
                                             float* __restrict__ wt1, float* __restrict__ wt2) {
    int i = blockIdx.x * 256 + threadIdx.x;
    if (i < 16 * 64 * 5) {
        int co = i & 15; int r = i >> 4; int k = r % 5; int ci = r / 5;
        wt1[i] = w1[(co * 64 + ci) * 5 + k];
    }
    int j = i - 16 * 64 * 5;
    if (j >= 0 && j < 32 * 16 * 5) {
        int co = j & 31; int r = j >> 5; int k = r % 5; int ci = r / 5;
        wt2[j] = w2[(co * 16 + ci) * 5 + k];
    }
}

// conv1: x[64,64,2048] -> relu -> pool2 -> h1[64,16,1024]
__global__ __launch_bounds__(256) void k_conv1(const float* __restrict__ x, const float* __restrict__ wt1,
                                               const float* __restrict__ b1, float* __restrict__ h1) {
    __shared__ float xs[16][260];
    __shared__ float ps[16][128];
    int tid = threadIdx.x;
    int tile = blockIdx.x;      // 0..7, 256 t each
    int b = blockIdx.y;
    int t0 = tile * 256;
    float acc[16];
    #pragma unroll
    for (int i = 0; i < 16; i++) acc[i] = 0.f;
    for (int cc = 0; cc < 4; cc++) {
        __syncthreads();
        for (int idx = tid; idx < 16 * 260; idx += 256) {
            int r = idx / 260, c = idx % 260;
            int gt = t0 + c - 2;
            float v = 0.f;
            if (gt >= 0 && gt < T_) v = x[((b * CIN + cc * 16 + r) * T_) + gt];
            xs[r][c] = v;
        }
        __syncthreads();
        for (int ci = 0; ci < 16; ci++) {
            float xv[5];
            #pragma unroll
            for (int j = 0; j < 5; j++) xv[j] = xs[ci][tid + j];
            const float* wp = wt1 + ((cc * 16 + ci) * 5) * 16;
            #pragma unroll
            for (int k = 0; k < 5; k++) {
                #pragma unroll
                for (int co = 0; co < 16; co++)
                    acc[co] = fmaf(xv[k], wp[k * 16 + co], acc[co]);
            }
        }
    }
    #pragma unroll
    for (int co = 0; co < 16; co++) {
        float a = fmaxf(acc[co] + b1[co], 0.f);
        float o = fmaxf(a, __shfl_xor(a, 1));
        if ((tid & 1) == 0) ps[co][tid >> 1] = o;
    }
    __syncthreads();
    for (int idx = tid; idx < 16 * 128; idx += 256) {
        int co = idx >> 7; int p = idx & 127;
        h1[(b * C1 + co) * T1 + tile * 128 + p] = ps[co][p];
    }
}

// conv2: h1[64,16,1024] -> relu -> pool2 -> xn[N,32] (node-major)
__global__ __launch_bounds__(256) void k_conv2(const float* __restrict__ h1, const float* __restrict__ wt2,
                                               const float* __restrict__ b2, float* __restrict__ xn) {
    __shared__ float xs[16][260];
    __shared__ float ps[128 * 32];
    int tid = threadIdx.x;
    int tile = blockIdx.x;      // 0..3
    int b = blockIdx.y;
    int t0 = tile * 256;
    float acc[32];
    #pragma unroll
    for (int i = 0; i < 32; i++) acc[i] = 0.f;
    for (int idx = tid; idx < 16 * 260; idx += 256) {
        int r = idx / 260, c = idx % 260;
        int gt = t0 + c - 2;
        float v = 0.f;
        if (gt >= 0 && gt < T1) v = h1[(b * C1 + r) * T1 + gt];
        xs[r][c] = v;
    }
    __syncthreads();
    for (int ci = 0; ci < 16; ci++) {
        float xv[5];
        #pragma unroll
        for (int j = 0; j < 5; j++) xv[j] = xs[ci][tid + j];
        const float* wp = wt2 + (ci * 5) * 32;
        #pragma unroll
        for (int k = 0; k < 5; k++) {
            #pragma unroll
            for (int co = 0; co < 32; co++)
                acc[co] = fmaf(xv[k], wp[k * 32 + co], acc[co]);
        }
    }
    #pragma unroll
    for (int co = 0; co < 32; co++) {
        float a = fmaxf(acc[co] + b2[co], 0.f);
        float o = fmaxf(a, __shfl_xor(a, 1));
        if ((tid & 1) == 0) ps[(tid >> 1) * 32 + co] = o;
    }
    __syncthreads();
    int base = (b * T2 + tile * 128) * 32;
    for (int idx = tid; idx < 128 * 32; idx += 256) xn[base + idx] = ps[idx];
}

// C[N,256] = A[N,K] @ W[K,256]; 128-row block tile, 8x16 microtile
__global__ __launch_bounds__(256, 2) void k_gemm(const float* __restrict__ A, const float* __restrict__ W,
                                                 float* __restrict__ Cb, int K) {
    __shared__ __align__(16) float xT[32 * 132];
    __shared__ __align__(16) float wl[32 * 256];
    int tid = threadIdx.x;
    int ty = tid >> 4, tx = tid & 15;
    int rows0 = blockIdx.x * 128;
    fx4 c[8][4];
    #pragma unroll
    for (int i = 0; i < 8; i++)
        #pragma unroll
        for (int j = 0; j < 4; j++) c[i][j] = (fx4){0.f, 0.f, 0.f, 0.f};

    for (int k0 = 0; k0 < K; k0 += 32) {
        __syncthreads();
        {   // stage A tile transposed: xT[k][r], ld 132 (bank-cycle breaker)
            int kq = tid & 7; int rbase = tid >> 3;
            #pragma unroll
            for (int rr0 = 0; rr0 < 128; rr0 += 32) {
                int r = rbase + rr0;
                fx4 v = *(const fx4*)&A[(size_t)(rows0 + r) * K + k0 + kq * 4];
                xT[(kq * 4 + 0) * 132 + r] = v.x;
                xT[(kq * 4 + 1) * 132 + r] = v.y;
                xT[(kq * 4 + 2) * 132 + r] = v.z;
                xT[(kq * 4 + 3) * 132 + r] = v.w;
            }
        }
        #pragma unroll
        for (int m = 0; m < 8; m++) {   // stage W tile [32][256]
            int idx = m * 1024 + tid * 4;
            *(fx4*)&wl[idx] = *(const fx4*)&W[(size_t)k0 * 256 + idx];
        }
        __syncthreads();
        #pragma unroll 4
        for (int kk = 0; kk < 32; kk++) {
            fx4 xa = *(const fx4*)&xT[kk * 132 + ty * 4];
            fx4 xb = *(const fx4*)&xT[kk * 132 + 64 + ty * 4];
            fx4 w[4];
            #pragma unroll
            for (int j = 0; j < 4; j++) w[j] = *(const fx4*)&wl[kk * 256 + tx * 4 + 64 * j];
            #pragma unroll
            for (int j = 0; j < 4; j++) {
                c[0][j] += xa.x * w[j];
                c[1][j] += xa.y * w[j];
                c[2][j] += xa.z * w[j];
                c[3][j] += xa.w * w[j];
                c[4][j] += xb.x * w[j];
                c[5][j] += xb.y * w[j];
                c[6][j] += xb.z * w[j];
                c[7][j] += xb.w * w[j];
            }
        }
    }
    #pragma unroll
    for (int i = 0; i < 8; i++) {
        int r = rows0 + ((i < 4) ? (ty * 4 + i) : (64 + ty * 4 + (i - 4)));
        #pragma unroll
        for (int j = 0; j < 4; j++)
            *(fx4*)&Cb[(size_t)r * 256 + tx * 4 + 64 * j] = c[i][j];
    }
}

// out[n,:] = relu( sum_{e in CSR[n]} xw[src_e,:]*norm_e + bias ); wave per node, lane owns float4
__global__ __launch_bounds__(256) void k_agg(const float* __restrict__ xw, const int* __restrict__ indptr,
                                             const int* __restrict__ csrc, const float* __restrict__ cnorm,
                                             const float* __restrict__ bias, float* __restrict__ outb) {
    int lane = threadIdx.x & 63;
    int n = blockIdx.x * 4 + (threadIdx.x >> 6);
    int beg = indptr[n], end = indptr[n + 1];
    fx4 acc = (fx4){0.f, 0.f, 0.f, 0.f};
    int e = beg;
    for (; e + 1 < end; e += 2) {
        int s0 = csrc[e], s1 = csrc[e + 1];
        float n0 = cnorm[e], n1 = cnorm[e + 1];
        fx4 v0 = *(const fx4*)&xw[(size_t)s0 * 256 + lane * 4];
        fx4 v1 = *(const fx4*)&xw[(size_t)s1 * 256 + lane * 4];
        acc += v0 * n0;
        acc += v1 * n1;
    }
    if (e < end) {
        int s0 = csrc[e]; float n0 = cnorm[e];
        fx4 v0 = *(const fx4*)&xw[(size_t)s0 * 256 + lane * 4];
        acc += v0 * n0;
    }
    fx4 bb = *(const fx4*)&bias[lane * 4];
    acc += bb;
    acc.x = fmaxf(acc.x, 0.f); acc.y = fmaxf(acc.y, 0.f);
    acc.z = fmaxf(acc.z, 0.f); acc.w = fmaxf(acc.w, 0.f);
    *(fx4*)&outb[(size_t)n * 256 + lane * 4] = acc;
}

__global__ __launch_bounds__(256) void k_mean(const float* __restrict__ hb, float* __restrict__ pooled) {
    int b = blockIdx.x >> 2, q = blockIdx.x & 3;
    int h = threadIdx.x;
    const float* p = hb + ((size_t)(b * T2 + q * 128)) * 256 + h;
    float s = 0.f;
    #pragma unroll 4
    for (int t = 0; t < 128; t++) s += p[(size_t)t * 256];
    atomicAdd(&pooled[b * HID + h], s * (1.f / 512.f));
}

__global__ __launch_bounds__(64) void k_cls(const float* __restrict__ pooled, const float* __restrict__ cw,
                                            const float* __restrict__ cb, float* __restrict__ outp) {
    int b = blockIdx.x, lane = threadIdx.x;
    float po[10];
    #pragma unroll
    for (int o = 0; o < 10; o++) po[o] = 0.f;
    #pragma unroll
    for (int m = 0; m < 4; m++) {
        int hh = lane + m * 64;
        float ph = pooled[b * HID + hh];
        #pragma unroll
        for (int o = 0; o < 10; o++) po[o] = fmaf(ph, cw[hh * 10 + o], po[o]);
    }
    #pragma unroll
    for (int off = 32; off >= 1; off >>= 1) {
        #pragma unroll
        for (int o = 0; o < 10; o++) po[o] += __shfl_down(po[o], off);
    }
    if (lane == 0) {
        #pragma unroll
        for (int o = 0; o < 10; o++) outp[b * 10 + o] = po[o] + cb[o];
    }
}

extern "C" void kernel_launch(void* const* d_in, const int* in_sizes, int n_in,
                              void* d_out, int out_size, void* d_ws, size_t ws_size,
                              hipStream_t stream) {
    const float* x   = (const float*)d_in[0];
    const int*   ei  = (const int*)d_in[1];
    const float* w1  = (const float*)d_in[2];
    const float* b1  = (const float*)d_in[3];
    const float* w2  = (const float*)d_in[4];
    const float* b2  = (const float*)d_in[5];
    const float* g1w = (const float*)d_in[6];
    const float* g1b = (const float*)d_in[7];
    const float* g2w = (const float*)d_in[8];
    const float* g2b = (const float*)d_in[9];
    const float* cw  = (const float*)d_in[10];
    const float* cb  = (const float*)d_in[11];
    float* out = (float*)d_out;
    char* ws = (char*)d_ws;

    float* A      = (float*)(ws + OFF_A);
    float* Bf     = (float*)(ws + OFF_B);
    float* xn     = (float*)(ws + OFF_XN);
    int*   deg    = (int*)(ws + OFF_DEG);
    int*   indptr = (int*)(ws + OFF_INDPTR);
    int*   cnt    = (int*)(ws + OFF_CNT);
    float* dinv   = (float*)(ws + OFF_DINV);
    int*   csrc   = (int*)(ws + OFF_CSRC);
    float* cnorm  = (float*)(ws + OFF_CNORM);
    float* wt1    = (float*)(ws + OFF_WT1);
    float* wt2    = (float*)(ws + OFF_WT2);
    float* pooled = (float*)(ws + OFF_POOL);
    float* h1 = A;  // h1 (4MB) aliases A; consumed by conv2 before gemm1 overwrites

    k_init <<<128, 256, 0, stream>>>(deg, cnt, pooled);
    k_twt  <<<30, 256, 0, stream>>>(w1, w2, wt1, wt2);
    k_count<<<2048, 256, 0, stream>>>(ei, deg);
    k_conv1<<<dim3(8, 64), 256, 0, stream>>>(x, wt1, b1, h1);
    k_dinv <<<128, 256, 0, stream>>>(deg, dinv);
    k_scan <<<1, 1024, 0, stream>>>(deg, indptr);
    k_fill <<<2176, 256, 0, stream>>>(ei, dinv, indptr, cnt, csrc, cnorm);
    k_conv2<<<dim3(4, 64), 256, 0, stream>>>(h1, wt2, b2, xn);
    k_gemm <<<256, 256, 0, stream>>>(xn, g1w, A, 32);
    k_agg  <<<8192, 256, 0, stream>>>(A, indptr, csrc, cnorm, g1b, Bf);
    k_gemm <<<256, 256, 0, stream>>>(Bf, g2w, A, 256);
    k_agg  <<<8192, 256, 0, stream>>>(A, indptr, csrc, cnorm, g2b, Bf);
    k_mean <<<256, 256, 0, stream>>>(Bf, pooled);
    k_cls  <<<64, 64, 0, stream>>>(pooled, cw, cb, out);
}

// Round 2
// 385.637 us; speedup vs baseline: 1.0501x; 1.0501x over previous
//
#include <hip/hip_runtime.h>

#define B_ 64
#define CIN 64
#define T_ 2048
#define C1 16
#define T1 1024
#define C2 32
#define T2 512
#define NN 32768
#define HID 256
#define OUTD 10
#define NE 524288
#define NTOT (NE + NN)

typedef __attribute__((ext_vector_type(4))) float fx4;

// ---- workspace byte offsets (total ~75.3 MB) ----
#define OFF_A      (0ull)                    // 32 MB: h1 (4MB) then xw
#define OFF_B      (32ull<<20)               // 32 MB: h / out
#define OFF_XN     (64ull<<20)               // 4 MB: node features [N][32]
#define OFF_DEG    (68ull<<20)               // 128 KB int
#define OFF_INDPTR ((68ull<<20) + (256u<<10))
#define OFF_CNT    ((68ull<<20) + (512u<<10))
#define OFF_DINV   ((68ull<<20) + (768u<<10))
#define OFF_CSRC   (69ull<<20)               // (E+N)*4 = 2.125 MB
#define OFF_CNORM  (72ull<<20)               // 2.125 MB
#define OFF_WT1    (75ull<<20)               // 20 KB
#define OFF_WT2    ((75ull<<20) + (64u<<10)) // 10 KB
#define OFF_POOL   ((75ull<<20) + (128u<<10))// 64 KB

__global__ __launch_bounds__(256) void k_init(int* deg, int* cnt, float* pooled) {
    int i = blockIdx.x * 256 + threadIdx.x;
    if (i < NN) { deg[i] = 1; cnt[i] = 0; }       // deg starts at 1 (self-loop)
    if (i < B_ * HID) pooled[i] = 0.f;
}

__global__ __launch_bounds__(256) void k_count(const int* __restrict__ ei, int* __restrict__ deg) {
    int e = blockIdx.x * 256 + threadIdx.x;
    if (e < NE) atomicAdd(&deg[ei[NE + e]], 1);
}

__global__ __launch_bounds__(256) void k_dinv(const int* __restrict__ deg, float* __restrict__ dinv) {
    int i = blockIdx.x * 256 + threadIdx.x;
    if (i < NN) dinv[i] = rsqrtf((float)deg[i]);
}

__global__ __launch_bounds__(1024) void k_scan(const int* __restrict__ deg, int* __restrict__ indptr) {
    __shared__ int sd[1024];
    int tid = threadIdx.x;
    int base = tid * 32;
    int loc[32]; int s = 0;
    #pragma unroll
    for (int j = 0; j < 32; j++) { loc[j] = deg[base + j]; s += loc[j]; }
    sd[tid] = s; __syncthreads();
    for (int off = 1; off < 1024; off <<= 1) {
        int v = (tid >= off) ? sd[tid - off] : 0;
        __syncthreads();
        if (tid >= off) sd[tid] += v;
        __syncthreads();
    }
    int run = sd[tid] - s;
    #pragma unroll
    for (int j = 0; j < 32; j++) { indptr[base + j] = run; run += loc[j]; }
    if (tid == 1023) indptr[NN] = run;
}

__global__ __launch_bounds__(256) void k_fill(const int* __restrict__ ei, const float* __restrict__ dinv,
                                              const int* __restrict__ indptr, int* __restrict__ cnt,
                                              int* __restrict__ csrc, float* __restrict__ cnorm) {
    int e = blockIdx.x * 256 + threadIdx.x;
    if (e >= NTOT) return;
    int s, d; float nrm;
    if (e < NE) { s = ei[e]; d = ei[NE + e]; nrm = dinv[s] * dinv[d]; }
    else        { s = d = e - NE;            nrm = dinv[s] * dinv[s]; }
    int pos = indptr[d] + atomicAdd(&cnt[d], 1);
    csrc[pos] = s; cnorm[pos] = nrm;
}

// transpose conv weights -> [ci][k][co] so inner loads are wave-uniform (scalar/L1 broadcast)
__global__ __launch_bounds__(256) void k_twt(const float* __restrict__ w1, const float* __restrict__ w2,
                                             float* __restrict__ wt1, float* __restrict__ wt2) {
    int i = blockIdx.x * 256 + threadIdx.x;
    if (i < 16 * 64 * 5) {
        int co = i & 15; int r = i >> 4; int k = r % 5; int ci = r / 5;
        wt1[i] = w1[(co * 64 + ci) * 5 + k];
    }
    int j = i - 16 * 64 * 5;
    if (j >= 0 && j < 32 * 16 * 5) {
        int co = j & 31; int r = j >> 5; int k = r % 5; int ci = r / 5;
        wt2[j] = w2[(co * 16 + ci) * 5 + k];
    }
}

// conv1: x[64,64,2048] -> relu -> pool2 -> h1[64,16,1024]
__global__ __launch_bounds__(256) void k_conv1(const float* __restrict__ x, const float* __restrict__ wt1,
                                               const float* __restrict__ b1, float* __restrict__ h1) {
    __shared__ float xs[16][260];
    __shared__ float ps[16][128];
    int tid = threadIdx.x;
    int tile = blockIdx.x;      // 0..7, 256 t each
    int b = blockIdx.y;
    int t0 = tile * 256;
    float acc[16];
    #pragma unroll
    for (int i = 0; i < 16; i++) acc[i] = 0.f;
    for (int cc = 0; cc < 4; cc++) {
        __syncthreads();
        for (int idx = tid; idx < 16 * 260; idx += 256) {
            int r = idx / 260, c = idx % 260;
            int gt = t0 + c - 2;
            float v = 0.f;
            if (gt >= 0 && gt < T_) v = x[((b * CIN + cc * 16 + r) * T_) + gt];
            xs[r][c] = v;
        }
        __syncthreads();
        for (int ci = 0; ci < 16; ci++) {
            float xv[5];
            #pragma unroll
            for (int j = 0; j < 5; j++) xv[j] = xs[ci][tid + j];
            const float* wp = wt1 + ((cc * 16 + ci) * 5) * 16;
            #pragma unroll
            for (int k = 0; k < 5; k++) {
                #pragma unroll
                for (int co = 0; co < 16; co++)
                    acc[co] = fmaf(xv[k], wp[k * 16 + co], acc[co]);
            }
        }
    }
    #pragma unroll
    for (int co = 0; co < 16; co++) {
        float a = fmaxf(acc[co] + b1[co], 0.f);
        float o = fmaxf(a, __shfl_xor(a, 1));
        if ((tid & 1) == 0) ps[co][tid >> 1] = o;
    }
    __syncthreads();
    for (int idx = tid; idx < 16 * 128; idx += 256) {
        int co = idx >> 7; int p = idx & 127;
        h1[(b * C1 + co) * T1 + tile * 128 + p] = ps[co][p];
    }
}

// conv2: h1[64,16,1024] -> relu -> pool2 -> xn[N,32] (node-major)
__global__ __launch_bounds__(256) void k_conv2(const float* __restrict__ h1, const float* __restrict__ wt2,
                                               const float* __restrict__ b2, float* __restrict__ xn) {
    __shared__ float xs[16][260];
    __shared__ float ps[128 * 32];
    int tid = threadIdx.x;
    int tile = blockIdx.x;      // 0..3
    int b = blockIdx.y;
    int t0 = tile * 256;
    float acc[32];
    #pragma unroll
    for (int i = 0; i < 32; i++) acc[i] = 0.f;
    for (int idx = tid; idx < 16 * 260; idx += 256) {
        int r = idx / 260, c = idx % 260;
        int gt = t0 + c - 2;
        float v = 0.f;
        if (gt >= 0 && gt < T1) v = h1[(b * C1 + r) * T1 + gt];
        xs[r][c] = v;
    }
    __syncthreads();
    for (int ci = 0; ci < 16; ci++) {
        float xv[5];
        #pragma unroll
        for (int j = 0; j < 5; j++) xv[j] = xs[ci][tid + j];
        const float* wp = wt2 + (ci * 5) * 32;
        #pragma unroll
        for (int k = 0; k < 5; k++) {
            #pragma unroll
            for (int co = 0; co < 32; co++)
                acc[co] = fmaf(xv[k], wp[k * 32 + co], acc[co]);
        }
    }
    #pragma unroll
    for (int co = 0; co < 32; co++) {
        float a = fmaxf(acc[co] + b2[co], 0.f);
        float o = fmaxf(a, __shfl_xor(a, 1));
        if ((tid & 1) == 0) ps[(tid >> 1) * 32 + co] = o;
    }
    __syncthreads();
    int base = (b * T2 + tile * 128) * 32;
    for (int idx = tid; idx < 128 * 32; idx += 256) xn[base + idx] = ps[idx];
}

// C[N,256] = A[N,K] @ W[K,256]; 128-row x 256-col block tile, 8x16 microtile.
// Double-buffered LDS + register-staged prefetch: global loads for tile t+1
// issue before compute of tile t (latency hides under ~8K cyc of FMAs).
// 1 block/CU (grid=256), so launch_bounds(256,1) frees full VGPR budget for
// deep unroll scheduling.
__global__ __launch_bounds__(256, 1) void k_gemm(const float* __restrict__ A, const float* __restrict__ W,
                                                 float* __restrict__ Cb, int K) {
    __shared__ __align__(16) float xT[2][32 * 132];   // [k][r], ld 132
    __shared__ __align__(16) float wl[2][32 * 256];   // [k][c]
    int tid = threadIdx.x;
    int ty = tid >> 4, tx = tid & 15;
    int rows0 = blockIdx.x * 128;
    int kq = tid & 7, rbase = tid >> 3;               // staging coords

    fx4 c[8][4];
    #pragma unroll
    for (int i = 0; i < 8; i++)
        #pragma unroll
        for (int j = 0; j < 4; j++) c[i][j] = (fx4){0.f, 0.f, 0.f, 0.f};

    int nt = K >> 5;
    fx4 ga[4], gw[8];

    // prologue: load tile 0 to regs, write LDS buf 0
    #pragma unroll
    for (int rr = 0; rr < 4; rr++)
        ga[rr] = *(const fx4*)&A[(size_t)(rows0 + rbase + 32 * rr) * K + kq * 4];
    #pragma unroll
    for (int m = 0; m < 8; m++)
        gw[m] = *(const fx4*)&W[(size_t)(m * 1024 + tid * 4)];
    {
        float* xq = xT[0]; float* wq = wl[0];
        #pragma unroll
        for (int rr = 0; rr < 4; rr++) {
            int r = rbase + 32 * rr;
            xq[(kq * 4 + 0) * 132 + r] = ga[rr].x;
            xq[(kq * 4 + 1) * 132 + r] = ga[rr].y;
            xq[(kq * 4 + 2) * 132 + r] = ga[rr].z;
            xq[(kq * 4 + 3) * 132 + r] = ga[rr].w;
        }
        #pragma unroll
        for (int m = 0; m < 8; m++)
            *(fx4*)&wq[m * 1024 + tid * 4] = gw[m];
    }
    __syncthreads();

    int cur = 0;
    for (int t = 0; t < nt; t++) {
        if (t + 1 < nt) {   // issue next tile's global loads (no wait)
            int k0 = (t + 1) << 5;
            #pragma unroll
            for (int rr = 0; rr < 4; rr++)
                ga[rr] = *(const fx4*)&A[(size_t)(rows0 + rbase + 32 * rr) * K + k0 + kq * 4];
            #pragma unroll
            for (int m = 0; m < 8; m++)
                gw[m] = *(const fx4*)&W[(size_t)k0 * 256 + m * 1024 + tid * 4];
        }
        const float* xp = xT[cur];
        const float* wp = wl[cur];
        #pragma unroll 8
        for (int kk = 0; kk < 32; kk++) {
            fx4 xa = *(const fx4*)&xp[kk * 132 + ty * 4];
            fx4 xb = *(const fx4*)&xp[kk * 132 + 64 + ty * 4];
            fx4 w[4];
            #pragma unroll
            for (int j = 0; j < 4; j++) w[j] = *(const fx4*)&wp[kk * 256 + tx * 4 + 64 * j];
            #pragma unroll
            for (int j = 0; j < 4; j++) {
                c[0][j] += xa.x * w[j];
                c[1][j] += xa.y * w[j];
                c[2][j] += xa.z * w[j];
                c[3][j] += xa.w * w[j];
                c[4][j] += xb.x * w[j];
                c[5][j] += xb.y * w[j];
                c[6][j] += xb.z * w[j];
                c[7][j] += xb.w * w[j];
            }
        }
        if (t + 1 < nt) {   // write prefetched tile to the other buffer
            float* xq = xT[cur ^ 1]; float* wq = wl[cur ^ 1];
            #pragma unroll
            for (int rr = 0; rr < 4; rr++) {
                int r = rbase + 32 * rr;
                xq[(kq * 4 + 0) * 132 + r] = ga[rr].x;
                xq[(kq * 4 + 1) * 132 + r] = ga[rr].y;
                xq[(kq * 4 + 2) * 132 + r] = ga[rr].z;
                xq[(kq * 4 + 3) * 132 + r] = ga[rr].w;
            }
            #pragma unroll
            for (int m = 0; m < 8; m++)
                *(fx4*)&wq[m * 1024 + tid * 4] = gw[m];
        }
        __syncthreads();
        cur ^= 1;
    }

    #pragma unroll
    for (int i = 0; i < 8; i++) {
        int r = rows0 + ((i < 4) ? (ty * 4 + i) : (64 + ty * 4 + (i - 4)));
        #pragma unroll
        for (int j = 0; j < 4; j++)
            *(fx4*)&Cb[(size_t)r * 256 + tx * 4 + 64 * j] = c[i][j];
    }
}

// out[n,:] = relu( sum_{e in CSR[n]} xw[src_e,:]*norm_e + bias ); wave per node, lane owns float4
__global__ __launch_bounds__(256) void k_agg(const float* __restrict__ xw, const int* __restrict__ indptr,
                                             const int* __restrict__ csrc, const float* __restrict__ cnorm,
                                             const float* __restrict__ bias, float* __restrict__ outb) {
    int lane = threadIdx.x & 63;
    int n = blockIdx.x * 4 + (threadIdx.x >> 6);
    int beg = indptr[n], end = indptr[n + 1];
    fx4 acc = (fx4){0.f, 0.f, 0.f, 0.f};
    int e = beg;
    for (; e + 1 < end; e += 2) {
        int s0 = csrc[e], s1 = csrc[e + 1];
        float n0 = cnorm[e], n1 = cnorm[e + 1];
        fx4 v0 = *(const fx4*)&xw[(size_t)s0 * 256 + lane * 4];
        fx4 v1 = *(const fx4*)&xw[(size_t)s1 * 256 + lane * 4];
        acc += v0 * n0;
        acc += v1 * n1;
    }
    if (e < end) {
        int s0 = csrc[e]; float n0 = cnorm[e];
        fx4 v0 = *(const fx4*)&xw[(size_t)s0 * 256 + lane * 4];
        acc += v0 * n0;
    }
    fx4 bb = *(const fx4*)&bias[lane * 4];
    acc += bb;
    acc.x = fmaxf(acc.x, 0.f); acc.y = fmaxf(acc.y, 0.f);
    acc.z = fmaxf(acc.z, 0.f); acc.w = fmaxf(acc.w, 0.f);
    *(fx4*)&outb[(size_t)n * 256 + lane * 4] = acc;
}

__global__ __launch_bounds__(256) void k_mean(const float* __restrict__ hb, float* __restrict__ pooled) {
    int b = blockIdx.x >> 2, q = blockIdx.x & 3;
    int h = threadIdx.x;
    const float* p = hb + ((size_t)(b * T2 + q * 128)) * 256 + h;
    float s = 0.f;
    #pragma unroll 4
    for (int t = 0; t < 128; t++) s += p[(size_t)t * 256];
    atomicAdd(&pooled[b * HID + h], s * (1.f / 512.f));
}

__global__ __launch_bounds__(64) void k_cls(const float* __restrict__ pooled, const float* __restrict__ cw,
                                            const float* __restrict__ cb, float* __restrict__ outp) {
    int b = blockIdx.x, lane = threadIdx.x;
    float po[10];
    #pragma unroll
    for (int o = 0; o < 10; o++) po[o] = 0.f;
    #pragma unroll
    for (int m = 0; m < 4; m++) {
        int hh = lane + m * 64;
        float ph = pooled[b * HID + hh];
        #pragma unroll
        for (int o = 0; o < 10; o++) po[o] = fmaf(ph, cw[hh * 10 + o], po[o]);
    }
    #pragma unroll
    for (int off = 32; off >= 1; off >>= 1) {
        #pragma unroll
        for (int o = 0; o < 10; o++) po[o] += __shfl_down(po[o], off);
    }
    if (lane == 0) {
        #pragma unroll
        for (int o = 0; o < 10; o++) outp[b * 10 + o] = po[o] + cb[o];
    }
}

extern "C" void kernel_launch(void* const* d_in, const int* in_sizes, int n_in,
                              void* d_out, int out_size, void* d_ws, size_t ws_size,
                              hipStream_t stream) {
    const float* x   = (const float*)d_in[0];
    const int*   ei  = (const int*)d_in[1];
    const float* w1  = (const float*)d_in[2];
    const float* b1  = (const float*)d_in[3];
    const float* w2  = (const float*)d_in[4];
    const float* b2  = (const float*)d_in[5];
    const float* g1w = (const float*)d_in[6];
    const float* g1b = (const float*)d_in[7];
    const float* g2w = (const float*)d_in[8];
    const float* g2b = (const float*)d_in[9];
    const float* cw  = (const float*)d_in[10];
    const float* cb  = (const float*)d_in[11];
    float* out = (float*)d_out;
    char* ws = (char*)d_ws;

    float* A      = (float*)(ws + OFF_A);
    float* Bf     = (float*)(ws + OFF_B);
    float* xn     = (float*)(ws + OFF_XN);
    int*   deg    = (int*)(ws + OFF_DEG);
    int*   indptr = (int*)(ws + OFF_INDPTR);
    int*   cnt    = (int*)(ws + OFF_CNT);
    float* dinv   = (float*)(ws + OFF_DINV);
    int*   csrc   = (int*)(ws + OFF_CSRC);
    float* cnorm  = (float*)(ws + OFF_CNORM);
    float* wt1    = (float*)(ws + OFF_WT1);
    float* wt2    = (float*)(ws + OFF_WT2);
    float* pooled = (float*)(ws + OFF_POOL);
    float* h1 = A;  // h1 (4MB) aliases A; consumed by conv2 before gemm1 overwrites

    k_init <<<128, 256, 0, stream>>>(deg, cnt, pooled);
    k_twt  <<<30, 256, 0, stream>>>(w1, w2, wt1, wt2);
    k_count<<<2048, 256, 0, stream>>>(ei, deg);
    k_conv1<<<dim3(8, 64), 256, 0, stream>>>(x, wt1, b1, h1);
    k_dinv <<<128, 256, 0, stream>>>(deg, dinv);
    k_scan <<<1, 1024, 0, stream>>>(deg, indptr);
    k_fill <<<2176, 256, 0, stream>>>(ei, dinv, indptr, cnt, csrc, cnorm);
    k_conv2<<<dim3(4, 64), 256, 0, stream>>>(h1, wt2, b2, xn);
    k_gemm <<<256, 256, 0, stream>>>(xn, g1w, A, 32);
    k_agg  <<<8192, 256, 0, stream>>>(A, indptr, csrc, cnorm, g1b, Bf);
    k_gemm <<<256, 256, 0, stream>>>(Bf, g2w, A, 256);
    k_agg  <<<8192, 256, 0, stream>>>(A, indptr, csrc, cnorm, g2b, Bf);
    k_mean <<<256, 256, 0, stream>>>(Bf, pooled);
    k_cls  <<<64, 64, 0, stream>>>(pooled, cw, cb, out);
}

// Round 3
// 295.933 us; speedup vs baseline: 1.3684x; 1.3031x over previous
//
#include <hip/hip_runtime.h>

#define B_ 64
#define CIN 64
#define T_ 2048
#define C1 16
#define T1 1024
#define C2 32
#define T2 512
#define NN 32768
#define HID 256
#define OUTD 10
#define NE 524288
#define NTOT (NE + NN)

typedef __attribute__((ext_vector_type(4))) float fx4;
typedef __attribute__((ext_vector_type(2))) float fx2;

// ---- workspace byte offsets (~67.2 MB) ----
#define OFF_H      (0ull)                    // 32 MB: H (gemm1 out) then H2 (agg2 out)
#define OFF_Z      (32ull<<20)               // 16 MB: gemm2 out, bf16 [N][256]
#define OFF_H1     (48ull<<20)               // 4 MB: conv1 out
#define OFF_XN     (52ull<<20)               // 4 MB: node features [N][32]
#define OFF_Y1     (56ull<<20)               // 4 MB: agg1 out [N][32]
#define OFF_DEG    (60ull<<20)               // 128 KB int
#define OFF_INDPTR ((60ull<<20) + (256u<<10))
#define OFF_CNT    ((60ull<<20) + (512u<<10))
#define OFF_DINV   ((60ull<<20) + (768u<<10))
#define OFF_CSRC   (61ull<<20)               // (E+N)*4 = 2.125 MB
#define OFF_CNORM  (64ull<<20)               // 2.125 MB
#define OFF_WT1    (67ull<<20)               // 20 KB
#define OFF_WT2    ((67ull<<20) + (64u<<10)) // 10 KB
#define OFF_POOL   ((67ull<<20) + (128u<<10))// 64 KB

__device__ __forceinline__ unsigned pk2_bf16(float a, float b) {
    unsigned ua = __float_as_uint(a), ub = __float_as_uint(b);
    ua = (ua + 0x7fffu + ((ua >> 16) & 1u)) >> 16;   // RNE
    ub = (ub + 0x7fffu + ((ub >> 16) & 1u)) >> 16;
    return ua | (ub << 16);
}

__global__ __launch_bounds__(256) void k_init(int* deg, int* cnt, float* pooled) {
    int i = blockIdx.x * 256 + threadIdx.x;
    if (i < NN) { deg[i] = 1; cnt[i] = 0; }       // deg starts at 1 (self-loop)
    if (i < B_ * HID) pooled[i] = 0.f;
}

__global__ __launch_bounds__(256) void k_count(const int* __restrict__ ei, int* __restrict__ deg) {
    int e = blockIdx.x * 256 + threadIdx.x;
    if (e < NE) atomicAdd(&deg[ei[NE + e]], 1);
}

__global__ __launch_bounds__(256) void k_dinv(const int* __restrict__ deg, float* __restrict__ dinv) {
    int i = blockIdx.x * 256 + threadIdx.x;
    if (i < NN) dinv[i] = rsqrtf((float)deg[i]);
}

__global__ __launch_bounds__(1024) void k_scan(const int* __restrict__ deg, int* __restrict__ indptr) {
    __shared__ int sd[1024];
    int tid = threadIdx.x;
    int base = tid * 32;
    int loc[32]; int s = 0;
    #pragma unroll
    for (int j = 0; j < 32; j++) { loc[j] = deg[base + j]; s += loc[j]; }
    sd[tid] = s; __syncthreads();
    for (int off = 1; off < 1024; off <<= 1) {
        int v = (tid >= off) ? sd[tid - off] : 0;
        __syncthreads();
        if (tid >= off) sd[tid] += v;
        __syncthreads();
    }
    int run = sd[tid] - s;
    #pragma unroll
    for (int j = 0; j < 32; j++) { indptr[base + j] = run; run += loc[j]; }
    if (tid == 1023) indptr[NN] = run;
}

__global__ __launch_bounds__(256) void k_fill(const int* __restrict__ ei, const float* __restrict__ dinv,
                                              const int* __restrict__ indptr, int* __restrict__ cnt,
                                              int* __restrict__ csrc, float* __restrict__ cnorm) {
    int e = blockIdx.x * 256 + threadIdx.x;
    if (e >= NTOT) return;
    int s, d; float nrm;
    if (e < NE) { s = ei[e]; d = ei[NE + e]; nrm = dinv[s] * dinv[d]; }
    else        { s = d = e - NE;            nrm = dinv[s] * dinv[s]; }
    int pos = indptr[d] + atomicAdd(&cnt[d], 1);
    csrc[pos] = s; cnorm[pos] = nrm;
}

// transpose conv weights -> [ci][k][co] so inner loads are wave-uniform (scalar/L1 broadcast)
__global__ __launch_bounds__(256) void k_twt(const float* __restrict__ w1, const float* __restrict__ w2,
                                             float* __restrict__ wt1, float* __restrict__ wt2) {
    int i = blockIdx.x * 256 + threadIdx.x;
    if (i < 16 * 64 * 5) {
        int co = i & 15; int r = i >> 4; int k = r % 5; int ci = r / 5;
        wt1[i] = w1[(co * 64 + ci) * 5 + k];
    }
    int j = i - 16 * 64 * 5;
    if (j >= 0 && j < 32 * 16 * 5) {
        int co = j & 31; int r = j >> 5; int k = r % 5; int ci = r / 5;
        wt2[j] = w2[(co * 16 + ci) * 5 + k];
    }
}

// conv1: x[64,64,2048] -> relu -> pool2 -> h1[64,16,1024]
__global__ __launch_bounds__(256) void k_conv1(const float* __restrict__ x, const float* __restrict__ wt1,
                                               const float* __restrict__ b1, float* __restrict__ h1) {
    __shared__ float xs[16][260];
    __shared__ float ps[16][128];
    int tid = threadIdx.x;
    int tile = blockIdx.x;      // 0..7, 256 t each
    int b = blockIdx.y;
    int t0 = tile * 256;
    float acc[16];
    #pragma unroll
    for (int i = 0; i < 16; i++) acc[i] = 0.f;
    for (int cc = 0; cc < 4; cc++) {
        __syncthreads();
        for (int idx = tid; idx < 16 * 260; idx += 256) {
            int r = idx / 260, c = idx % 260;
            int gt = t0 + c - 2;
            float v = 0.f;
            if (gt >= 0 && gt < T_) v = x[((b * CIN + cc * 16 + r) * T_) + gt];
            xs[r][c] = v;
        }
        __syncthreads();
        for (int ci = 0; ci < 16; ci++) {
            float xv[5];
            #pragma unroll
            for (int j = 0; j < 5; j++) xv[j] = xs[ci][tid + j];
            const float* wp = wt1 + ((cc * 16 + ci) * 5) * 16;
            #pragma unroll
            for (int k = 0; k < 5; k++) {
                #pragma unroll
                for (int co = 0; co < 16; co++)
                    acc[co] = fmaf(xv[k], wp[k * 16 + co], acc[co]);
            }
        }
    }
    #pragma unroll
    for (int co = 0; co < 16; co++) {
        float a = fmaxf(acc[co] + b1[co], 0.f);
        float o = fmaxf(a, __shfl_xor(a, 1));
        if ((tid & 1) == 0) ps[co][tid >> 1] = o;
    }
    __syncthreads();
    for (int idx = tid; idx < 16 * 128; idx += 256) {
        int co = idx >> 7; int p = idx & 127;
        h1[(b * C1 + co) * T1 + tile * 128 + p] = ps[co][p];
    }
}

// conv2: h1[64,16,1024] -> relu -> pool2 -> xn[N,32] (node-major)
__global__ __launch_bounds__(256) void k_conv2(const float* __restrict__ h1, const float* __restrict__ wt2,
                                               const float* __restrict__ b2, float* __restrict__ xn) {
    __shared__ float xs[16][260];
    __shared__ float ps[128 * 32];
    int tid = threadIdx.x;
    int tile = blockIdx.x;      // 0..3
    int b = blockIdx.y;
    int t0 = tile * 256;
    float acc[32];
    #pragma unroll
    for (int i = 0; i < 32; i++) acc[i] = 0.f;
    for (int idx = tid; idx < 16 * 260; idx += 256) {
        int r = idx / 260, c = idx % 260;
        int gt = t0 + c - 2;
        float v = 0.f;
        if (gt >= 0 && gt < T1) v = h1[(b * C1 + r) * T1 + gt];
        xs[r][c] = v;
    }
    __syncthreads();
    for (int ci = 0; ci < 16; ci++) {
        float xv[5];
        #pragma unroll
        for (int j = 0; j < 5; j++) xv[j] = xs[ci][tid + j];
        const float* wp = wt2 + (ci * 5) * 32;
        #pragma unroll
        for (int k = 0; k < 5; k++) {
            #pragma unroll
            for (int co = 0; co < 32; co++)
                acc[co] = fmaf(xv[k], wp[k * 32 + co], acc[co]);
        }
    }
    #pragma unroll
    for (int co = 0; co < 32; co++) {
        float a = fmaxf(acc[co] + b2[co], 0.f);
        float o = fmaxf(a, __shfl_xor(a, 1));
        if ((tid & 1) == 0) ps[(tid >> 1) * 32 + co] = o;
    }
    __syncthreads();
    int base = (b * T2 + tile * 128) * 32;
    for (int idx = tid; idx < 128 * 32; idx += 256) xn[base + idx] = ps[idx];
}

// agg over 32-wide features: y1[n,:] = sum_e norm_e * xn[src_e,:]
// wave per node, 4 edge-slots x 16 lanes (fx2 per lane), shfl reduce.
__global__ __launch_bounds__(256) void k_agg32(const float* __restrict__ xn, const int* __restrict__ indptr,
                                               const int* __restrict__ csrc, const float* __restrict__ cnorm,
                                               float* __restrict__ y1) {
    int lane = threadIdx.x & 63;
    int n = blockIdx.x * 4 + (threadIdx.x >> 6);
    int slot = lane >> 4;
    int f2 = (lane & 15) * 2;
    int beg = indptr[n], end = indptr[n + 1];
    float ax = 0.f, ay = 0.f;
    for (int e = beg; e < end; e += 4) {
        int ee = e + slot;
        bool ok = ee < end;
        int s = ok ? csrc[ee] : 0;
        float nm = ok ? cnorm[ee] : 0.f;
        fx2 v = *(const fx2*)&xn[(size_t)s * 32 + f2];
        ax = fmaf(v.x, nm, ax);
        ay = fmaf(v.y, nm, ay);
    }
    ax += __shfl_xor(ax, 16); ay += __shfl_xor(ay, 16);
    ax += __shfl_xor(ax, 32); ay += __shfl_xor(ay, 32);
    if (lane < 16) *(fx2*)&y1[(size_t)n * 32 + f2] = (fx2){ax, ay};
}

// C[N,256] = A[N,K] @ W[K,256]; 128x256 block tile, 8x16 microtile, LDS double-buffer
// + register prefetch. MODE 1: out = relu(C + bias) f32. MODE 2: out = bf16(C).
template<int MODE>
__global__ __launch_bounds__(256, 1) void k_gemm(const float* __restrict__ A, const float* __restrict__ W,
                                                 const float* __restrict__ bias, void* __restrict__ Cb, int K) {
    __shared__ __align__(16) float xT[2][32 * 132];   // [k][r], ld 132
    __shared__ __align__(16) float wl[2][32 * 256];   // [k][c]
    int tid = threadIdx.x;
    int ty = tid >> 4, tx = tid & 15;
    int rows0 = blockIdx.x * 128;
    int kq = tid & 7, rbase = tid >> 3;               // staging coords

    fx4 c[8][4];
    #pragma unroll
    for (int i = 0; i < 8; i++)
        #pragma unroll
        for (int j = 0; j < 4; j++) c[i][j] = (fx4){0.f, 0.f, 0.f, 0.f};

    int nt = K >> 5;
    fx4 ga[4], gw[8];

    // prologue: load tile 0 to regs, write LDS buf 0
    #pragma unroll
    for (int rr = 0; rr < 4; rr++)
        ga[rr] = *(const fx4*)&A[(size_t)(rows0 + rbase + 32 * rr) * K + kq * 4];
    #pragma unroll
    for (int m = 0; m < 8; m++)
        gw[m] = *(const fx4*)&W[(size_t)(m * 1024 + tid * 4)];
    {
        float* xq = xT[0]; float* wq = wl[0];
        #pragma unroll
        for (int rr = 0; rr < 4; rr++) {
            int r = rbase + 32 * rr;
            xq[(kq * 4 + 0) * 132 + r] = ga[rr].x;
            xq[(kq * 4 + 1) * 132 + r] = ga[rr].y;
            xq[(kq * 4 + 2) * 132 + r] = ga[rr].z;
            xq[(kq * 4 + 3) * 132 + r] = ga[rr].w;
        }
        #pragma unroll
        for (int m = 0; m < 8; m++)
            *(fx4*)&wq[m * 1024 + tid * 4] = gw[m];
    }
    __syncthreads();

    int cur = 0;
    for (int t = 0; t < nt; t++) {
        if (t + 1 < nt) {   // issue next tile's global loads (no wait)
            int k0 = (t + 1) << 5;
            #pragma unroll
            for (int rr = 0; rr < 4; rr++)
                ga[rr] = *(const fx4*)&A[(size_t)(rows0 + rbase + 32 * rr) * K + k0 + kq * 4];
            #pragma unroll
            for (int m = 0; m < 8; m++)
                gw[m] = *(const fx4*)&W[(size_t)k0 * 256 + m * 1024 + tid * 4];
        }
        const float* xp = xT[cur];
        const float* wp = wl[cur];
        #pragma unroll 8
        for (int kk = 0; kk < 32; kk++) {
            fx4 xa = *(const fx4*)&xp[kk * 132 + ty * 4];
            fx4 xb = *(const fx4*)&xp[kk * 132 + 64 + ty * 4];
            fx4 w[4];
            #pragma unroll
            for (int j = 0; j < 4; j++) w[j] = *(const fx4*)&wp[kk * 256 + tx * 4 + 64 * j];
            #pragma unroll
            for (int j = 0; j < 4; j++) {
                c[0][j] += xa.x * w[j];
                c[1][j] += xa.y * w[j];
                c[2][j] += xa.z * w[j];
                c[3][j] += xa.w * w[j];
                c[4][j] += xb.x * w[j];
                c[5][j] += xb.y * w[j];
                c[6][j] += xb.z * w[j];
                c[7][j] += xb.w * w[j];
            }
        }
        if (t + 1 < nt) {   // write prefetched tile to the other buffer
            float* xq = xT[cur ^ 1]; float* wq = wl[cur ^ 1];
            #pragma unroll
            for (int rr = 0; rr < 4; rr++) {
                int r = rbase + 32 * rr;
                xq[(kq * 4 + 0) * 132 + r] = ga[rr].x;
                xq[(kq * 4 + 1) * 132 + r] = ga[rr].y;
                xq[(kq * 4 + 2) * 132 + r] = ga[rr].z;
                xq[(kq * 4 + 3) * 132 + r] = ga[rr].w;
            }
            #pragma unroll
            for (int m = 0; m < 8; m++)
                *(fx4*)&wq[m * 1024 + tid * 4] = gw[m];
        }
        __syncthreads();
        cur ^= 1;
    }

    if (MODE == 1) {
        float* Cf = (float*)Cb;
        fx4 bb[4];
        #pragma unroll
        for (int j = 0; j < 4; j++) bb[j] = *(const fx4*)&bias[tx * 4 + 64 * j];
        #pragma unroll
        for (int i = 0; i < 8; i++) {
            int r = rows0 + ((i < 4) ? (ty * 4 + i) : (64 + ty * 4 + (i - 4)));
            #pragma unroll
            for (int j = 0; j < 4; j++) {
                fx4 v = c[i][j] + bb[j];
                v.x = fmaxf(v.x, 0.f); v.y = fmaxf(v.y, 0.f);
                v.z = fmaxf(v.z, 0.f); v.w = fmaxf(v.w, 0.f);
                *(fx4*)&Cf[(size_t)r * 256 + tx * 4 + 64 * j] = v;
            }
        }
    } else {
        unsigned short* Ch = (unsigned short*)Cb;
        #pragma unroll
        for (int i = 0; i < 8; i++) {
            int r = rows0 + ((i < 4) ? (ty * 4 + i) : (64 + ty * 4 + (i - 4)));
            #pragma unroll
            for (int j = 0; j < 4; j++) {
                fx4 v = c[i][j];
                uint2 p;
                p.x = pk2_bf16(v.x, v.y);
                p.y = pk2_bf16(v.z, v.w);
                *(uint2*)&Ch[(size_t)r * 256 + tx * 4 + 64 * j] = p;
            }
        }
    }
}

// out[n,:] = relu( sum_e Z[src_e,:]*norm_e + bias ); Z is bf16 [N][256].
// wave per node, lane owns 4 features (8B gather), fp32 accumulate.
__global__ __launch_bounds__(256) void k_aggb(const unsigned short* __restrict__ Z, const int* __restrict__ indptr,
                                              const int* __restrict__ csrc, const float* __restrict__ cnorm,
                                              const float* __restrict__ bias, float* __restrict__ outb) {
    int lane = threadIdx.x & 63;
    int n = blockIdx.x * 4 + (threadIdx.x >> 6);
    int beg = indptr[n], end = indptr[n + 1];
    fx4 acc = (fx4){0.f, 0.f, 0.f, 0.f};
    int e = beg;
    for (; e + 1 < end; e += 2) {
        int s0 = csrc[e], s1 = csrc[e + 1];
        float n0 = cnorm[e], n1 = cnorm[e + 1];
        uint2 w0 = *(const uint2*)&Z[(size_t)s0 * 256 + lane * 4];
        uint2 w1 = *(const uint2*)&Z[(size_t)s1 * 256 + lane * 4];
        acc.x = fmaf(__uint_as_float(w0.x << 16), n0, acc.x);
        acc.y = fmaf(__uint_as_float(w0.x & 0xffff0000u), n0, acc.y);
        acc.z = fmaf(__uint_as_float(w0.y << 16), n0, acc.z);
        acc.w = fmaf(__uint_as_float(w0.y & 0xffff0000u), n0, acc.w);
        acc.x = fmaf(__uint_as_float(w1.x << 16), n1, acc.x);
        acc.y = fmaf(__uint_as_float(w1.x & 0xffff0000u), n1, acc.y);
        acc.z = fmaf(__uint_as_float(w1.y << 16), n1, acc.z);
        acc.w = fmaf(__uint_as_float(w1.y & 0xffff0000u), n1, acc.w);
    }
    if (e < end) {
        int s0 = csrc[e]; float n0 = cnorm[e];
        uint2 w0 = *(const uint2*)&Z[(size_t)s0 * 256 + lane * 4];
        acc.x = fmaf(__uint_as_float(w0.x << 16), n0, acc.x);
        acc.y = fmaf(__uint_as_float(w0.x & 0xffff0000u), n0, acc.y);
        acc.z = fmaf(__uint_as_float(w0.y << 16), n0, acc.z);
        acc.w = fmaf(__uint_as_float(w0.y & 0xffff0000u), n0, acc.w);
    }
    fx4 bb = *(const fx4*)&bias[lane * 4];
    acc += bb;
    acc.x = fmaxf(acc.x, 0.f); acc.y = fmaxf(acc.y, 0.f);
    acc.z = fmaxf(acc.z, 0.f); acc.w = fmaxf(acc.w, 0.f);
    *(fx4*)&outb[(size_t)n * 256 + lane * 4] = acc;
}

__global__ __launch_bounds__(256) void k_mean(const float* __restrict__ hb, float* __restrict__ pooled) {
    int b = blockIdx.x >> 2, q = blockIdx.x & 3;
    int h = threadIdx.x;
    const float* p = hb + ((size_t)(b * T2 + q * 128)) * 256 + h;
    float s = 0.f;
    #pragma unroll 4
    for (int t = 0; t < 128; t++) s += p[(size_t)t * 256];
    atomicAdd(&pooled[b * HID + h], s * (1.f / 512.f));
}

__global__ __launch_bounds__(64) void k_cls(const float* __restrict__ pooled, const float* __restrict__ cw,
                                            const float* __restrict__ cb, float* __restrict__ outp) {
    int b = blockIdx.x, lane = threadIdx.x;
    float po[10];
    #pragma unroll
    for (int o = 0; o < 10; o++) po[o] = 0.f;
    #pragma unroll
    for (int m = 0; m < 4; m++) {
        int hh = lane + m * 64;
        float ph = pooled[b * HID + hh];
        #pragma unroll
        for (int o = 0; o < 10; o++) po[o] = fmaf(ph, cw[hh * 10 + o], po[o]);
    }
    #pragma unroll
    for (int off = 32; off >= 1; off >>= 1) {
        #pragma unroll
        for (int o = 0; o < 10; o++) po[o] += __shfl_down(po[o], off);
    }
    if (lane == 0) {
        #pragma unroll
        for (int o = 0; o < 10; o++) outp[b * 10 + o] = po[o] + cb[o];
    }
}

extern "C" void kernel_launch(void* const* d_in, const int* in_sizes, int n_in,
                              void* d_out, int out_size, void* d_ws, size_t ws_size,
                              hipStream_t stream) {
    const float* x   = (const float*)d_in[0];
    const int*   ei  = (const int*)d_in[1];
    const float* w1  = (const float*)d_in[2];
    const float* b1  = (const float*)d_in[3];
    const float* w2  = (const float*)d_in[4];
    const float* b2  = (const float*)d_in[5];
    const float* g1w = (const float*)d_in[6];
    const float* g1b = (const float*)d_in[7];
    const float* g2w = (const float*)d_in[8];
    const float* g2b = (const float*)d_in[9];
    const float* cw  = (const float*)d_in[10];
    const float* cb  = (const float*)d_in[11];
    float* out = (float*)d_out;
    char* ws = (char*)d_ws;

    float*          H      = (float*)(ws + OFF_H);     // H then H2
    unsigned short* Z      = (unsigned short*)(ws + OFF_Z);
    float*          h1     = (float*)(ws + OFF_H1);
    float*          xn     = (float*)(ws + OFF_XN);
    float*          y1     = (float*)(ws + OFF_Y1);
    int*            deg    = (int*)(ws + OFF_DEG);
    int*            indptr = (int*)(ws + OFF_INDPTR);
    int*            cnt    = (int*)(ws + OFF_CNT);
    float*          dinv   = (float*)(ws + OFF_DINV);
    int*            csrc   = (int*)(ws + OFF_CSRC);
    float*          cnorm  = (float*)(ws + OFF_CNORM);
    float*          wt1    = (float*)(ws + OFF_WT1);
    float*          wt2    = (float*)(ws + OFF_WT2);
    float*          pooled = (float*)(ws + OFF_POOL);

    k_init <<<128, 256, 0, stream>>>(deg, cnt, pooled);
    k_twt  <<<30, 256, 0, stream>>>(w1, w2, wt1, wt2);
    k_count<<<2048, 256, 0, stream>>>(ei, deg);
    k_conv1<<<dim3(8, 64), 256, 0, stream>>>(x, wt1, b1, h1);
    k_dinv <<<128, 256, 0, stream>>>(deg, dinv);
    k_scan <<<1, 1024, 0, stream>>>(deg, indptr);
    k_fill <<<2176, 256, 0, stream>>>(ei, dinv, indptr, cnt, csrc, cnorm);
    k_conv2<<<dim3(4, 64), 256, 0, stream>>>(h1, wt2, b2, xn);
    k_agg32<<<8192, 256, 0, stream>>>(xn, indptr, csrc, cnorm, y1);          // y1 = Â·X  (32-wide)
    k_gemm<1><<<256, 256, 0, stream>>>(y1, g1w, g1b, (void*)H, 32);          // H = relu(y1@W1 + b1)
    k_gemm<2><<<256, 256, 0, stream>>>(H, g2w, nullptr, (void*)Z, 256);      // Z = bf16(H@W2)
    k_aggb <<<8192, 256, 0, stream>>>(Z, indptr, csrc, cnorm, g2b, H);       // H2 = relu(Â·Z + b2)
    k_mean <<<256, 256, 0, stream>>>(H, pooled);
    k_cls  <<<64, 64, 0, stream>>>(pooled, cw, cb, out);
}

// Round 4
// 270.452 us; speedup vs baseline: 1.4974x; 1.0942x over previous
//
#include <hip/hip_runtime.h>

#define B_ 64
#define CIN 64
#define T_ 2048
#define C1 16
#define T1 1024
#define C2 32
#define T2 512
#define NN 32768
#define HID 256
#define OUTD 10
#define NE 524288
#define NTOT (NE + NN)

typedef __attribute__((ext_vector_type(4))) float fx4;
typedef __attribute__((ext_vector_type(2))) float fx2;
typedef __attribute__((ext_vector_type(8))) _Float16 hx8;
typedef __attribute__((ext_vector_type(4))) _Float16 hx4;

// ---- workspace byte offsets (~67.5 MB; harness ws proven >= 75 MB) ----
#define OFF_H      (0ull)                    // 16 MB: H fp16 [N][256]; later H2 fp32 [N][256] (32 MB)
#define OFF_Z      (32ull<<20)               // 16 MB: gemm2 out, fp16 [N][256]
#define OFF_H1     (48ull<<20)               // 4 MB: conv1 out
#define OFF_XN     (52ull<<20)               // 4 MB: node features [N][32]
#define OFF_Y1     (56ull<<20)               // 4 MB: agg1 out [N][32]
#define OFF_DEG    (60ull<<20)               // 128 KB int
#define OFF_INDPTR ((60ull<<20) + (256u<<10))
#define OFF_CNT    ((60ull<<20) + (512u<<10))
#define OFF_DINV   ((60ull<<20) + (768u<<10))
#define OFF_CSRC   (61ull<<20)               // (E+N)*4 = 2.125 MB
#define OFF_CNORM  (64ull<<20)               // 2.125 MB
#define OFF_WT1    (67ull<<20)               // 20 KB
#define OFF_WT2    ((67ull<<20) + (64u<<10)) // 10 KB
#define OFF_POOL   ((67ull<<20) + (128u<<10))// 64 KB
#define OFF_W2T    ((67ull<<20) + (256u<<10))// 128 KB: W2^T fp16 [256 n][256 k]

__global__ __launch_bounds__(256) void k_init(int* deg, int* cnt, float* pooled) {
    int i = blockIdx.x * 256 + threadIdx.x;
    if (i < NN) { deg[i] = 1; cnt[i] = 0; }       // deg starts at 1 (self-loop)
    if (i < B_ * HID) pooled[i] = 0.f;
}

__global__ __launch_bounds__(256) void k_count(const int* __restrict__ ei, int* __restrict__ deg) {
    int e = blockIdx.x * 256 + threadIdx.x;
    if (e < NE) atomicAdd(&deg[ei[NE + e]], 1);
}

__global__ __launch_bounds__(256) void k_dinv(const int* __restrict__ deg, float* __restrict__ dinv) {
    int i = blockIdx.x * 256 + threadIdx.x;
    if (i < NN) dinv[i] = rsqrtf((float)deg[i]);
}

__global__ __launch_bounds__(1024) void k_scan(const int* __restrict__ deg, int* __restrict__ indptr) {
    __shared__ int sd[1024];
    int tid = threadIdx.x;
    int base = tid * 32;
    int loc[32]; int s = 0;
    #pragma unroll
    for (int j = 0; j < 32; j++) { loc[j] = deg[base + j]; s += loc[j]; }
    sd[tid] = s; __syncthreads();
    for (int off = 1; off < 1024; off <<= 1) {
        int v = (tid >= off) ? sd[tid - off] : 0;
        __syncthreads();
        if (tid >= off) sd[tid] += v;
        __syncthreads();
    }
    int run = sd[tid] - s;
    #pragma unroll
    for (int j = 0; j < 32; j++) { indptr[base + j] = run; run += loc[j]; }
    if (tid == 1023) indptr[NN] = run;
}

__global__ __launch_bounds__(256) void k_fill(const int* __restrict__ ei, const float* __restrict__ dinv,
                                              const int* __restrict__ indptr, int* __restrict__ cnt,
                                              int* __restrict__ csrc, float* __restrict__ cnorm) {
    int e = blockIdx.x * 256 + threadIdx.x;
    if (e >= NTOT) return;
    int s, d; float nrm;
    if (e < NE) { s = ei[e]; d = ei[NE + e]; nrm = dinv[s] * dinv[d]; }
    else        { s = d = e - NE;            nrm = dinv[s] * dinv[s]; }
    int pos = indptr[d] + atomicAdd(&cnt[d], 1);
    csrc[pos] = s; cnorm[pos] = nrm;
}

// transpose conv weights -> [ci][k][co] so inner loads are wave-uniform (scalar/L1 broadcast)
__global__ __launch_bounds__(256) void k_twt(const float* __restrict__ w1, const float* __restrict__ w2,
                                             float* __restrict__ wt1, float* __restrict__ wt2) {
    int i = blockIdx.x * 256 + threadIdx.x;
    if (i < 16 * 64 * 5) {
        int co = i & 15; int r = i >> 4; int k = r % 5; int ci = r / 5;
        wt1[i] = w1[(co * 64 + ci) * 5 + k];
    }
    int j = i - 16 * 64 * 5;
    if (j >= 0 && j < 32 * 16 * 5) {
        int co = j & 31; int r = j >> 5; int k = r % 5; int ci = r / 5;
        wt2[j] = w2[(co * 16 + ci) * 5 + k];
    }
}

// W2 [256 k][256 n] fp32 -> W2T [256 n][256 k] fp16, LDS-tiled transpose
__global__ __launch_bounds__(256) void k_cvtw(const float* __restrict__ w, _Float16* __restrict__ wt) {
    __shared__ float tl[64][65];
    int bx = blockIdx.x & 3, by = blockIdx.x >> 2;   // k-tile, n-tile
    int t = threadIdx.x;
    #pragma unroll
    for (int it = 0; it < 16; it++) {
        int idx = it * 256 + t;
        int r = idx >> 6, c = idx & 63;
        tl[r][c] = w[(size_t)(bx * 64 + r) * 256 + by * 64 + c];
    }
    __syncthreads();
    #pragma unroll
    for (int it = 0; it < 16; it++) {
        int idx = it * 256 + t;
        int r = idx >> 6, c = idx & 63;
        wt[(size_t)(by * 64 + r) * 256 + bx * 64 + c] = (_Float16)tl[c][r];
    }
}

// conv1: x[64,64,2048] -> relu -> pool2 -> h1[64,16,1024]
__global__ __launch_bounds__(256) void k_conv1(const float* __restrict__ x, const float* __restrict__ wt1,
                                               const float* __restrict__ b1, float* __restrict__ h1) {
    __shared__ float xs[16][260];
    __shared__ float ps[16][128];
    int tid = threadIdx.x;
    int tile = blockIdx.x;      // 0..7, 256 t each
    int b = blockIdx.y;
    int t0 = tile * 256;
    float acc[16];
    #pragma unroll
    for (int i = 0; i < 16; i++) acc[i] = 0.f;
    for (int cc = 0; cc < 4; cc++) {
        __syncthreads();
        for (int idx = tid; idx < 16 * 260; idx += 256) {
            int r = idx / 260, c = idx % 260;
            int gt = t0 + c - 2;
            float v = 0.f;
            if (gt >= 0 && gt < T_) v = x[((b * CIN + cc * 16 + r) * T_) + gt];
            xs[r][c] = v;
        }
        __syncthreads();
        for (int ci = 0; ci < 16; ci++) {
            float xv[5];
            #pragma unroll
            for (int j = 0; j < 5; j++) xv[j] = xs[ci][tid + j];
            const float* wp = wt1 + ((cc * 16 + ci) * 5) * 16;
            #pragma unroll
            for (int k = 0; k < 5; k++) {
                #pragma unroll
                for (int co = 0; co < 16; co++)
                    acc[co] = fmaf(xv[k], wp[k * 16 + co], acc[co]);
            }
        }
    }
    #pragma unroll
    for (int co = 0; co < 16; co++) {
        float a = fmaxf(acc[co] + b1[co], 0.f);
        float o = fmaxf(a, __shfl_xor(a, 1));
        if ((tid & 1) == 0) ps[co][tid >> 1] = o;
    }
    __syncthreads();
    for (int idx = tid; idx < 16 * 128; idx += 256) {
        int co = idx >> 7; int p = idx & 127;
        h1[(b * C1 + co) * T1 + tile * 128 + p] = ps[co][p];
    }
}

// conv2: h1[64,16,1024] -> relu -> pool2 -> xn[N,32] (node-major)
__global__ __launch_bounds__(256) void k_conv2(const float* __restrict__ h1, const float* __restrict__ wt2,
                                               const float* __restrict__ b2, float* __restrict__ xn) {
    __shared__ float xs[16][260];
    __shared__ float ps[128 * 32];
    int tid = threadIdx.x;
    int tile = blockIdx.x;      // 0..3
    int b = blockIdx.y;
    int t0 = tile * 256;
    float acc[32];
    #pragma unroll
    for (int i = 0; i < 32; i++) acc[i] = 0.f;
    for (int idx = tid; idx < 16 * 260; idx += 256) {
        int r = idx / 260, c = idx % 260;
        int gt = t0 + c - 2;
        float v = 0.f;
        if (gt >= 0 && gt < T1) v = h1[(b * C1 + r) * T1 + gt];
        xs[r][c] = v;
    }
    __syncthreads();
    for (int ci = 0; ci < 16; ci++) {
        float xv[5];
        #pragma unroll
        for (int j = 0; j < 5; j++) xv[j] = xs[ci][tid + j];
        const float* wp = wt2 + (ci * 5) * 32;
        #pragma unroll
        for (int k = 0; k < 5; k++) {
            #pragma unroll
            for (int co = 0; co < 32; co++)
                acc[co] = fmaf(xv[k], wp[k * 32 + co], acc[co]);
        }
    }
    #pragma unroll
    for (int co = 0; co < 32; co++) {
        float a = fmaxf(acc[co] + b2[co], 0.f);
        float o = fmaxf(a, __shfl_xor(a, 1));
        if ((tid & 1) == 0) ps[(tid >> 1) * 32 + co] = o;
    }
    __syncthreads();
    int base = (b * T2 + tile * 128) * 32;
    for (int idx = tid; idx < 128 * 32; idx += 256) xn[base + idx] = ps[idx];
}

// agg over 32-wide features: y1[n,:] = sum_e norm_e * xn[src_e,:]
__global__ __launch_bounds__(256) void k_agg32(const float* __restrict__ xn, const int* __restrict__ indptr,
                                               const int* __restrict__ csrc, const float* __restrict__ cnorm,
                                               float* __restrict__ y1) {
    int lane = threadIdx.x & 63;
    int n = blockIdx.x * 4 + (threadIdx.x >> 6);
    int slot = lane >> 4;
    int f2 = (lane & 15) * 2;
    int beg = indptr[n], end = indptr[n + 1];
    float ax = 0.f, ay = 0.f;
    for (int e = beg; e < end; e += 4) {
        int ee = e + slot;
        bool ok = ee < end;
        int s = ok ? csrc[ee] : 0;
        float nm = ok ? cnorm[ee] : 0.f;
        fx2 v = *(const fx2*)&xn[(size_t)s * 32 + f2];
        ax = fmaf(v.x, nm, ax);
        ay = fmaf(v.y, nm, ay);
    }
    ax += __shfl_xor(ax, 16); ay += __shfl_xor(ay, 16);
    ax += __shfl_xor(ax, 32); ay += __shfl_xor(ay, 32);
    if (lane < 16) *(fx2*)&y1[(size_t)n * 32 + f2] = (fx2){ax, ay};
}

// gemm1: H[N,256] = fp16( relu(y1[N,32] @ W1[32,256] + b1) ). Single K pass,
// 49.7 KB LDS -> 3 blocks/CU.
__global__ __launch_bounds__(256, 3) void k_gemm1(const float* __restrict__ A, const float* __restrict__ W,
                                                  const float* __restrict__ bias, _Float16* __restrict__ H) {
    __shared__ __align__(16) float xT[32 * 132];
    __shared__ __align__(16) float wl[32 * 256];
    int tid = threadIdx.x;
    int ty = tid >> 4, tx = tid & 15;
    int rows0 = blockIdx.x * 128;
    int kq = tid & 7, rbase = tid >> 3;
    #pragma unroll
    for (int rr = 0; rr < 4; rr++) {
        int r = rbase + 32 * rr;
        fx4 v = *(const fx4*)&A[(size_t)(rows0 + r) * 32 + kq * 4];
        xT[(kq * 4 + 0) * 132 + r] = v.x;
        xT[(kq * 4 + 1) * 132 + r] = v.y;
        xT[(kq * 4 + 2) * 132 + r] = v.z;
        xT[(kq * 4 + 3) * 132 + r] = v.w;
    }
    #pragma unroll
    for (int m = 0; m < 8; m++)
        *(fx4*)&wl[m * 1024 + tid * 4] = *(const fx4*)&W[(size_t)(m * 1024 + tid * 4)];
    __syncthreads();

    fx4 c[8][4];
    #pragma unroll
    for (int i = 0; i < 8; i++)
        #pragma unroll
        for (int j = 0; j < 4; j++) c[i][j] = (fx4){0.f, 0.f, 0.f, 0.f};

    #pragma unroll 8
    for (int kk = 0; kk < 32; kk++) {
        fx4 xa = *(const fx4*)&xT[kk * 132 + ty * 4];
        fx4 xb = *(const fx4*)&xT[kk * 132 + 64 + ty * 4];
        fx4 w[4];
        #pragma unroll
        for (int j = 0; j < 4; j++) w[j] = *(const fx4*)&wl[kk * 256 + tx * 4 + 64 * j];
        #pragma unroll
        for (int j = 0; j < 4; j++) {
            c[0][j] += xa.x * w[j];
            c[1][j] += xa.y * w[j];
            c[2][j] += xa.z * w[j];
            c[3][j] += xa.w * w[j];
            c[4][j] += xb.x * w[j];
            c[5][j] += xb.y * w[j];
            c[6][j] += xb.z * w[j];
            c[7][j] += xb.w * w[j];
        }
    }
    fx4 bb[4];
    #pragma unroll
    for (int j = 0; j < 4; j++) bb[j] = *(const fx4*)&bias[tx * 4 + 64 * j];
    #pragma unroll
    for (int i = 0; i < 8; i++) {
        int r = rows0 + ((i < 4) ? (ty * 4 + i) : (64 + ty * 4 + (i - 4)));
        #pragma unroll
        for (int j = 0; j < 4; j++) {
            fx4 v = c[i][j] + bb[j];
            hx4 h;
            h.x = (_Float16)fmaxf(v.x, 0.f);
            h.y = (_Float16)fmaxf(v.y, 0.f);
            h.z = (_Float16)fmaxf(v.z, 0.f);
            h.w = (_Float16)fmaxf(v.w, 0.f);
            *(hx4*)&H[(size_t)r * 256 + tx * 4 + 64 * j] = h;
        }
    }
}

// gemm2 MFMA: Z[N,256] = fp16( H[N,256] @ W2 ), A/B fp16, fp32 accumulate.
// 128x128 tile, BK=64, 4 waves (2x2, 64x64 each), double-buffered LDS (73.7 KB
// -> 2 blocks/CU). Frag layout (guide m89/m92-verified): A/B = 8 contiguous
// halves along K at row/col lane&15, k-offset (lane>>4)*8; D: col=lane&15,
// row=(lane>>4)*4+reg. +8-half row pad keeps ds_read_b128 at minimum cycles.
#define LDH 72
__global__ __launch_bounds__(256, 2) void k_gemm2m(const _Float16* __restrict__ A,
                                                   const _Float16* __restrict__ Bt,
                                                   _Float16* __restrict__ Z) {
    __shared__ __align__(16) _Float16 As[2][128 * LDH];
    __shared__ __align__(16) _Float16 Bs[2][128 * LDH];
    int tid = threadIdx.x;
    int lane = tid & 63, wid = tid >> 6;
    int wm = wid >> 1, wn = wid & 1;
    int row0 = blockIdx.x * 128, col0 = blockIdx.y * 128;
    int l15 = lane & 15, g = lane >> 4;
    int sr = tid >> 3, sc = tid & 7;   // staging: row-within-32-group, 16B chunk

    fx4 acc[4][4];
    #pragma unroll
    for (int m = 0; m < 4; m++)
        #pragma unroll
        for (int n = 0; n < 4; n++) acc[m][n] = (fx4){0.f, 0.f, 0.f, 0.f};

    uint4 ga[4], gb[4];
    #pragma unroll
    for (int it = 0; it < 4; it++) {
        ga[it] = *(const uint4*)&A[(size_t)(row0 + sr + 32 * it) * 256 + sc * 8];
        gb[it] = *(const uint4*)&Bt[(size_t)(col0 + sr + 32 * it) * 256 + sc * 8];
    }
    #pragma unroll
    for (int it = 0; it < 4; it++) {
        *(uint4*)&As[0][(sr + 32 * it) * LDH + sc * 8] = ga[it];
        *(uint4*)&Bs[0][(sr + 32 * it) * LDH + sc * 8] = gb[it];
    }
    __syncthreads();

    int cur = 0;
    for (int t = 0; t < 4; t++) {
        if (t < 3) {
            int k0 = (t + 1) * 64;
            #pragma unroll
            for (int it = 0; it < 4; it++) {
                ga[it] = *(const uint4*)&A[(size_t)(row0 + sr + 32 * it) * 256 + k0 + sc * 8];
                gb[it] = *(const uint4*)&Bt[(size_t)(col0 + sr + 32 * it) * 256 + k0 + sc * 8];
            }
        }
        const _Float16* ap = As[cur];
        const _Float16* bp = Bs[cur];
        hx8 af[4][2], bf[4][2];
        #pragma unroll
        for (int m = 0; m < 4; m++)
            #pragma unroll
            for (int ks = 0; ks < 2; ks++)
                af[m][ks] = *(const hx8*)&ap[(wm * 64 + m * 16 + l15) * LDH + ks * 32 + g * 8];
        #pragma unroll
        for (int n = 0; n < 4; n++)
            #pragma unroll
            for (int ks = 0; ks < 2; ks++)
                bf[n][ks] = *(const hx8*)&bp[(wn * 64 + n * 16 + l15) * LDH + ks * 32 + g * 8];
        #pragma unroll
        for (int m = 0; m < 4; m++)
            #pragma unroll
            for (int n = 0; n < 4; n++) {
                acc[m][n] = __builtin_amdgcn_mfma_f32_16x16x32_f16(af[m][0], bf[n][0], acc[m][n], 0, 0, 0);
                acc[m][n] = __builtin_amdgcn_mfma_f32_16x16x32_f16(af[m][1], bf[n][1], acc[m][n], 0, 0, 0);
            }
        if (t < 3) {
            #pragma unroll
            for (int it = 0; it < 4; it++) {
                *(uint4*)&As[cur ^ 1][(sr + 32 * it) * LDH + sc * 8] = ga[it];
                *(uint4*)&Bs[cur ^ 1][(sr + 32 * it) * LDH + sc * 8] = gb[it];
            }
        }
        __syncthreads();
        cur ^= 1;
    }

    #pragma unroll
    for (int m = 0; m < 4; m++)
        #pragma unroll
        for (int n = 0; n < 4; n++) {
            int cc = col0 + wn * 64 + n * 16 + l15;
            #pragma unroll
            for (int r = 0; r < 4; r++) {
                int rr = row0 + wm * 64 + m * 16 + g * 4 + r;
                Z[(size_t)rr * 256 + cc] = (_Float16)acc[m][n][r];
            }
        }
}

// out[n,:] = relu( sum_e Z[src_e,:]*norm_e + bias ); Z fp16 [N][256].
__global__ __launch_bounds__(256) void k_aggb(const _Float16* __restrict__ Z, const int* __restrict__ indptr,
                                              const int* __restrict__ csrc, const float* __restrict__ cnorm,
                                              const float* __restrict__ bias, float* __restrict__ outb) {
    int lane = threadIdx.x & 63;
    int n = blockIdx.x * 4 + (threadIdx.x >> 6);
    int beg = indptr[n], end = indptr[n + 1];
    fx4 acc = (fx4){0.f, 0.f, 0.f, 0.f};
    int e = beg;
    for (; e + 1 < end; e += 2) {
        int s0 = csrc[e], s1 = csrc[e + 1];
        float n0 = cnorm[e], n1 = cnorm[e + 1];
        hx4 v0 = *(const hx4*)&Z[(size_t)s0 * 256 + lane * 4];
        hx4 v1 = *(const hx4*)&Z[(size_t)s1 * 256 + lane * 4];
        acc.x = fmaf((float)v0.x, n0, acc.x);
        acc.y = fmaf((float)v0.y, n0, acc.y);
        acc.z = fmaf((float)v0.z, n0, acc.z);
        acc.w = fmaf((float)v0.w, n0, acc.w);
        acc.x = fmaf((float)v1.x, n1, acc.x);
        acc.y = fmaf((float)v1.y, n1, acc.y);
        acc.z = fmaf((float)v1.z, n1, acc.z);
        acc.w = fmaf((float)v1.w, n1, acc.w);
    }
    if (e < end) {
        int s0 = csrc[e]; float n0 = cnorm[e];
        hx4 v0 = *(const hx4*)&Z[(size_t)s0 * 256 + lane * 4];
        acc.x = fmaf((float)v0.x, n0, acc.x);
        acc.y = fmaf((float)v0.y, n0, acc.y);
        acc.z = fmaf((float)v0.z, n0, acc.z);
        acc.w = fmaf((float)v0.w, n0, acc.w);
    }
    fx4 bb = *(const fx4*)&bias[lane * 4];
    acc += bb;
    acc.x = fmaxf(acc.x, 0.f); acc.y = fmaxf(acc.y, 0.f);
    acc.z = fmaxf(acc.z, 0.f); acc.w = fmaxf(acc.w, 0.f);
    *(fx4*)&outb[(size_t)n * 256 + lane * 4] = acc;
}

__global__ __launch_bounds__(256) void k_mean(const float* __restrict__ hb, float* __restrict__ pooled) {
    int b = blockIdx.x >> 2, q = blockIdx.x & 3;
    int h = threadIdx.x;
    const float* p = hb + ((size_t)(b * T2 + q * 128)) * 256 + h;
    float s = 0.f;
    #pragma unroll 4
    for (int t = 0; t < 128; t++) s += p[(size_t)t * 256];
    atomicAdd(&pooled[b * HID + h], s * (1.f / 512.f));
}

__global__ __launch_bounds__(64) void k_cls(const float* __restrict__ pooled, const float* __restrict__ cw,
                                            const float* __restrict__ cb, float* __restrict__ outp) {
    int b = blockIdx.x, lane = threadIdx.x;
    float po[10];
    #pragma unroll
    for (int o = 0; o < 10; o++) po[o] = 0.f;
    #pragma unroll
    for (int m = 0; m < 4; m++) {
        int hh = lane + m * 64;
        float ph = pooled[b * HID + hh];
        #pragma unroll
        for (int o = 0; o < 10; o++) po[o] = fmaf(ph, cw[hh * 10 + o], po[o]);
    }
    #pragma unroll
    for (int off = 32; off >= 1; off >>= 1) {
        #pragma unroll
        for (int o = 0; o < 10; o++) po[o] += __shfl_down(po[o], off);
    }
    if (lane == 0) {
        #pragma unroll
        for (int o = 0; o < 10; o++) outp[b * 10 + o] = po[o] + cb[o];
    }
}

extern "C" void kernel_launch(void* const* d_in, const int* in_sizes, int n_in,
                              void* d_out, int out_size, void* d_ws, size_t ws_size,
                              hipStream_t stream) {
    const float* x   = (const float*)d_in[0];
    const int*   ei  = (const int*)d_in[1];
    const float* w1  = (const float*)d_in[2];
    const float* b1  = (const float*)d_in[3];
    const float* w2  = (const float*)d_in[4];
    const float* b2  = (const float*)d_in[5];
    const float* g1w = (const float*)d_in[6];
    const float* g1b = (const float*)d_in[7];
    const float* g2w = (const float*)d_in[8];
    const float* g2b = (const float*)d_in[9];
    const float* cw  = (const float*)d_in[10];
    const float* cb  = (const float*)d_in[11];
    float* out = (float*)d_out;
    char* ws = (char*)d_ws;

    _Float16*       H      = (_Float16*)(ws + OFF_H);
    float*          H2     = (float*)(ws + OFF_H);     // reuses H region after gemm2
    _Float16*       Z      = (_Float16*)(ws + OFF_Z);
    float*          h1     = (float*)(ws + OFF_H1);
    float*          xn     = (float*)(ws + OFF_XN);
    float*          y1     = (float*)(ws + OFF_Y1);
    int*            deg    = (int*)(ws + OFF_DEG);
    int*            indptr = (int*)(ws + OFF_INDPTR);
    int*            cnt    = (int*)(ws + OFF_CNT);
    float*          dinv   = (float*)(ws + OFF_DINV);
    int*            csrc   = (int*)(ws + OFF_CSRC);
    float*          cnorm  = (float*)(ws + OFF_CNORM);
    float*          wt1    = (float*)(ws + OFF_WT1);
    float*          wt2    = (float*)(ws + OFF_WT2);
    float*          pooled = (float*)(ws + OFF_POOL);
    _Float16*       w2t    = (_Float16*)(ws + OFF_W2T);

    k_init <<<128, 256, 0, stream>>>(deg, cnt, pooled);
    k_twt  <<<30, 256, 0, stream>>>(w1, w2, wt1, wt2);
    k_cvtw <<<16, 256, 0, stream>>>(g2w, w2t);
    k_count<<<2048, 256, 0, stream>>>(ei, deg);
    k_conv1<<<dim3(8, 64), 256, 0, stream>>>(x, wt1, b1, h1);
    k_dinv <<<128, 256, 0, stream>>>(deg, dinv);
    k_scan <<<1, 1024, 0, stream>>>(deg, indptr);
    k_fill <<<2176, 256, 0, stream>>>(ei, dinv, indptr, cnt, csrc, cnorm);
    k_conv2<<<dim3(4, 64), 256, 0, stream>>>(h1, wt2, b2, xn);
    k_agg32<<<8192, 256, 0, stream>>>(xn, indptr, csrc, cnorm, y1);          // y1 = A^ . X (32-wide)
    k_gemm1<<<256, 256, 0, stream>>>(y1, g1w, g1b, H);                       // H = fp16(relu(y1@W1+b1))
    k_gemm2m<<<dim3(256, 2), 256, 0, stream>>>(H, w2t, Z);                   // Z = fp16(H@W2)
    k_aggb <<<8192, 256, 0, stream>>>(Z, indptr, csrc, cnorm, g2b, H2);      // H2 = relu(A^ . Z + b2)
    k_mean <<<256, 256, 0, stream>>>(H2, pooled);
    k_cls  <<<64, 64, 0, stream>>>(pooled, cw, cb, out);
}

// Round 5
// 229.870 us; speedup vs baseline: 1.7617x; 1.1765x over previous
//
#include <hip/hip_runtime.h>

#define B_ 64
#define CIN 64
#define T_ 2048
#define C1 16
#define T1 1024
#define C2 32
#define T2 512
#define NN 32768
#define HID 256
#define OUTD 10
#define NE 524288
#define NTOT (NE + NN)

typedef __attribute__((ext_vector_type(4))) float fx4;
typedef __attribute__((ext_vector_type(2))) float fx2;
typedef __attribute__((ext_vector_type(8))) _Float16 hx8;
typedef __attribute__((ext_vector_type(4))) _Float16 hx4;

// ---- workspace byte offsets ----
#define OFF_H      (0ull)                    // 16 MB: H fp16 [N][256]; later H2 fp32 [N][256] (32 MB)
#define OFF_Z      (32ull<<20)               // 16 MB: gemm2 out, fp16 [N][256]
#define OFF_H1     (48ull<<20)               // 4 MB: conv1 out
#define OFF_XN     (52ull<<20)               // 4 MB: node features [N][32]
#define OFF_Y1     (56ull<<20)               // 4 MB: agg1 out [N][32]
#define OFF_DEG    (60ull<<20)               // 128 KB int
#define OFF_INDPTR ((60ull<<20) + (256u<<10))
#define OFF_CNT    ((60ull<<20) + (512u<<10))
#define OFF_DINV   ((60ull<<20) + (768u<<10))
#define OFF_CSRC   (61ull<<20)               // (E+N)*4 = 2.125 MB
#define OFF_CNORM  (64ull<<20)               // 2.125 MB
#define OFF_WT1    (67ull<<20)               // 20 KB
#define OFF_WT2    ((67ull<<20) + (64u<<10)) // 10 KB
#define OFF_POOL   ((67ull<<20) + (128u<<10))// 64 KB
#define OFF_W2T    ((67ull<<20) + (256u<<10))// 128 KB: W2^T fp16 [256 n][256 k]

// setup: blocks 0..127 init deg/cnt/pooled; 128..143 cvtw (W2->W2T fp16);
// 144..173 twt (conv weight transpose)
__global__ __launch_bounds__(256) void k_setup(int* deg, int* cnt, float* pooled,
                                               const float* __restrict__ w1, const float* __restrict__ w2,
                                               float* __restrict__ wt1, float* __restrict__ wt2,
                                               const float* __restrict__ gw2, _Float16* __restrict__ w2t) {
    __shared__ float tl[64][65];
    int blk = blockIdx.x, t = threadIdx.x;
    if (blk < 128) {
        int i = blk * 256 + t;
        if (i < NN) { deg[i] = 1; cnt[i] = 0; }   // deg starts at 1 (self-loop)
        if (i < B_ * HID) pooled[i] = 0.f;
    } else if (blk < 144) {
        int bb = blk - 128;
        int bx = bb & 3, by = bb >> 2;            // k-tile, n-tile
        #pragma unroll
        for (int it = 0; it < 16; it++) {
            int idx = it * 256 + t;
            int r = idx >> 6, c = idx & 63;
            tl[r][c] = gw2[(size_t)(bx * 64 + r) * 256 + by * 64 + c];
        }
        __syncthreads();
        #pragma unroll
        for (int it = 0; it < 16; it++) {
            int idx = it * 256 + t;
            int r = idx >> 6, c = idx & 63;
            w2t[(size_t)(by * 64 + r) * 256 + bx * 64 + c] = (_Float16)tl[c][r];
        }
    } else {
        int i = (blk - 144) * 256 + t;
        if (i < 16 * 64 * 5) {
            int co = i & 15; int r = i >> 4; int k = r % 5; int ci = r / 5;
            wt1[i] = w1[(co * 64 + ci) * 5 + k];
        }
        int j = i - 16 * 64 * 5;
        if (j >= 0 && j < 32 * 16 * 5) {
            int co = j & 31; int r = j >> 5; int k = r % 5; int ci = r / 5;
            wt2[j] = w2[(co * 16 + ci) * 5 + k];
        }
    }
}

__global__ __launch_bounds__(256) void k_count(const int* __restrict__ ei, int* __restrict__ deg) {
    int e = blockIdx.x * 256 + threadIdx.x;
    if (e < NE) atomicAdd(&deg[ei[NE + e]], 1);
}

// scan also emits dinv = rsqrt(deg)
__global__ __launch_bounds__(1024) void k_scan(const int* __restrict__ deg, int* __restrict__ indptr,
                                               float* __restrict__ dinv) {
    __shared__ int sd[1024];
    int tid = threadIdx.x;
    int base = tid * 32;
    int loc[32]; int s = 0;
    #pragma unroll
    for (int j = 0; j < 32; j++) { loc[j] = deg[base + j]; s += loc[j]; }
    #pragma unroll
    for (int j = 0; j < 32; j++) dinv[base + j] = rsqrtf((float)loc[j]);
    sd[tid] = s; __syncthreads();
    for (int off = 1; off < 1024; off <<= 1) {
        int v = (tid >= off) ? sd[tid - off] : 0;
        __syncthreads();
        if (tid >= off) sd[tid] += v;
        __syncthreads();
    }
    int run = sd[tid] - s;
    #pragma unroll
    for (int j = 0; j < 32; j++) { indptr[base + j] = run; run += loc[j]; }
    if (tid == 1023) indptr[NN] = run;
}

__global__ __launch_bounds__(256) void k_fill(const int* __restrict__ ei, const float* __restrict__ dinv,
                                              const int* __restrict__ indptr, int* __restrict__ cnt,
                                              int* __restrict__ csrc, float* __restrict__ cnorm) {
    int e = blockIdx.x * 256 + threadIdx.x;
    if (e >= NTOT) return;
    int s, d; float nrm;
    if (e < NE) { s = ei[e]; d = ei[NE + e]; nrm = dinv[s] * dinv[d]; }
    else        { s = d = e - NE;            nrm = dinv[s] * dinv[s]; }
    int pos = indptr[d] + atomicAdd(&cnt[d], 1);
    csrc[pos] = s; cnorm[pos] = nrm;
}

// conv1: x[64,64,2048] -> relu -> pool2 -> h1[64,16,1024]
// Single-phase: stage ALL 64 ci rows (66.6 KB LDS, fx4 loads, one barrier),
// then one straight 5120-FMA run with wave-uniform weight s_loads.
__global__ __launch_bounds__(256) void k_conv1(const float* __restrict__ x, const float* __restrict__ wt1,
                                               const float* __restrict__ b1, float* __restrict__ h1) {
    __shared__ float xs[64][260];
    __shared__ float ps[16][128];
    int tid = threadIdx.x;
    int tile = blockIdx.x;      // 0..7, 256 t each
    int b = blockIdx.y;
    int t0 = tile * 256;
    const float* xb = x + ((size_t)b * CIN) * T_ + t0;
    {   // interior cols 0..255 -> xs[r][2..257], 16 fx4 per thread
        int f = tid & 63, r0 = tid >> 6;
        #pragma unroll
        for (int it = 0; it < 16; it++) {
            int r = r0 + 4 * it;
            fx4 v = *(const fx4*)&xb[(size_t)r * T_ + f * 4];
            *(fx4*)&xs[r][2 + f * 4] = v;
        }
        // halo cols {-2,-1,256,257} -> xs[r][{0,1,258,259}], 1 per thread
        int r = tid >> 2, c = tid & 3;
        int off = (c < 2) ? (c - 2) : (254 + c);
        int gt = t0 + off;
        float v = 0.f;
        if (gt >= 0 && gt < T_) v = xb[(size_t)r * T_ + off];
        xs[r][2 + off] = v;
    }
    __syncthreads();
    float acc[16];
    #pragma unroll
    for (int i = 0; i < 16; i++) acc[i] = 0.f;
    for (int ci = 0; ci < 64; ci++) {
        float xv[5];
        #pragma unroll
        for (int j = 0; j < 5; j++) xv[j] = xs[ci][tid + j];
        const float* wp = wt1 + ci * 80;
        #pragma unroll
        for (int k = 0; k < 5; k++) {
            #pragma unroll
            for (int co = 0; co < 16; co++)
                acc[co] = fmaf(xv[k], wp[k * 16 + co], acc[co]);
        }
    }
    #pragma unroll
    for (int co = 0; co < 16; co++) {
        float a = fmaxf(acc[co] + b1[co], 0.f);
        float o = fmaxf(a, __shfl_xor(a, 1));
        if ((tid & 1) == 0) ps[co][tid >> 1] = o;
    }
    __syncthreads();
    for (int idx = tid; idx < 16 * 128; idx += 256) {
        int co = idx >> 7; int p = idx & 127;
        h1[(b * C1 + co) * T1 + tile * 128 + p] = ps[co][p];
    }
}

// conv2: h1[64,16,1024] -> relu -> pool2 -> xn[N,32] (node-major)
__global__ __launch_bounds__(256) void k_conv2(const float* __restrict__ h1, const float* __restrict__ wt2,
                                               const float* __restrict__ b2, float* __restrict__ xn) {
    __shared__ float xs[16][260];
    __shared__ float ps[128 * 32];
    int tid = threadIdx.x;
    int tile = blockIdx.x;      // 0..3
    int b = blockIdx.y;
    int t0 = tile * 256;
    float acc[32];
    #pragma unroll
    for (int i = 0; i < 32; i++) acc[i] = 0.f;
    for (int idx = tid; idx < 16 * 260; idx += 256) {
        int r = idx / 260, c = idx % 260;
        int gt = t0 + c - 2;
        float v = 0.f;
        if (gt >= 0 && gt < T1) v = h1[(b * C1 + r) * T1 + gt];
        xs[r][c] = v;
    }
    __syncthreads();
    for (int ci = 0; ci < 16; ci++) {
        float xv[5];
        #pragma unroll
        for (int j = 0; j < 5; j++) xv[j] = xs[ci][tid + j];
        const float* wp = wt2 + (ci * 5) * 32;
        #pragma unroll
        for (int k = 0; k < 5; k++) {
            #pragma unroll
            for (int co = 0; co < 32; co++)
                acc[co] = fmaf(xv[k], wp[k * 32 + co], acc[co]);
        }
    }
    #pragma unroll
    for (int co = 0; co < 32; co++) {
        float a = fmaxf(acc[co] + b2[co], 0.f);
        float o = fmaxf(a, __shfl_xor(a, 1));
        if ((tid & 1) == 0) ps[(tid >> 1) * 32 + co] = o;
    }
    __syncthreads();
    int base = (b * T2 + tile * 128) * 32;
    for (int idx = tid; idx < 128 * 32; idx += 256) xn[base + idx] = ps[idx];
}

// agg over 32-wide features: y1[n,:] = sum_e norm_e * xn[src_e,:]
__global__ __launch_bounds__(256) void k_agg32(const float* __restrict__ xn, const int* __restrict__ indptr,
                                               const int* __restrict__ csrc, const float* __restrict__ cnorm,
                                               float* __restrict__ y1) {
    int lane = threadIdx.x & 63;
    int n = blockIdx.x * 4 + (threadIdx.x >> 6);
    int slot = lane >> 4;
    int f2 = (lane & 15) * 2;
    int beg = indptr[n], end = indptr[n + 1];
    float ax = 0.f, ay = 0.f;
    for (int e = beg; e < end; e += 4) {
        int ee = e + slot;
        bool ok = ee < end;
        int s = ok ? csrc[ee] : 0;
        float nm = ok ? cnorm[ee] : 0.f;
        fx2 v = *(const fx2*)&xn[(size_t)s * 32 + f2];
        ax = fmaf(v.x, nm, ax);
        ay = fmaf(v.y, nm, ay);
    }
    ax += __shfl_xor(ax, 16); ay += __shfl_xor(ay, 16);
    ax += __shfl_xor(ax, 32); ay += __shfl_xor(ay, 32);
    if (lane < 16) *(fx2*)&y1[(size_t)n * 32 + f2] = (fx2){ax, ay};
}

// gemm1: H[N,256] = fp16( relu(y1[N,32] @ W1[32,256] + b1) ).
// 64-row tiles x 512 blocks (2 blocks/CU), cols tx*8+128j -> 16B fp16 stores.
__global__ __launch_bounds__(256) void k_gemm1(const float* __restrict__ A, const float* __restrict__ W,
                                               const float* __restrict__ bias, _Float16* __restrict__ H) {
    __shared__ __align__(16) float xT[32 * 68];   // [k][r], 64 rows + pad
    __shared__ __align__(16) float wl[32 * 256];
    int tid = threadIdx.x;
    int ty = tid >> 4, tx = tid & 15;
    int rows0 = blockIdx.x * 64;
    int kq = tid & 7, rs = tid >> 3;              // staging coords (rs 0..31)
    {
        fx4 v0 = *(const fx4*)&A[(size_t)(rows0 + rs) * 32 + kq * 4];
        fx4 v1 = *(const fx4*)&A[(size_t)(rows0 + rs + 32) * 32 + kq * 4];
        #pragma unroll
        for (int i = 0; i < 4; i++) {
            xT[(kq * 4 + i) * 68 + rs]      = v0[i];
            xT[(kq * 4 + i) * 68 + rs + 32] = v1[i];
        }
    }
    #pragma unroll
    for (int m = 0; m < 8; m++)
        *(fx4*)&wl[m * 1024 + tid * 4] = *(const fx4*)&W[(size_t)(m * 1024 + tid * 4)];
    __syncthreads();

    fx4 c[4][4];
    #pragma unroll
    for (int i = 0; i < 4; i++)
        #pragma unroll
        for (int j = 0; j < 4; j++) c[i][j] = (fx4){0.f, 0.f, 0.f, 0.f};

    #pragma unroll 8
    for (int kk = 0; kk < 32; kk++) {
        fx4 xa = *(const fx4*)&xT[kk * 68 + ty * 4];
        fx4 w[4];
        w[0] = *(const fx4*)&wl[kk * 256 + tx * 8];
        w[1] = *(const fx4*)&wl[kk * 256 + tx * 8 + 4];
        w[2] = *(const fx4*)&wl[kk * 256 + tx * 8 + 128];
        w[3] = *(const fx4*)&wl[kk * 256 + tx * 8 + 132];
        #pragma unroll
        for (int j = 0; j < 4; j++) {
            c[0][j] += xa.x * w[j];
            c[1][j] += xa.y * w[j];
            c[2][j] += xa.z * w[j];
            c[3][j] += xa.w * w[j];
        }
    }
    fx4 bb[4];
    bb[0] = *(const fx4*)&bias[tx * 8];
    bb[1] = *(const fx4*)&bias[tx * 8 + 4];
    bb[2] = *(const fx4*)&bias[tx * 8 + 128];
    bb[3] = *(const fx4*)&bias[tx * 8 + 132];
    #pragma unroll
    for (int i = 0; i < 4; i++) {
        int r = rows0 + ty * 4 + i;
        fx4 v0 = c[i][0] + bb[0], v1 = c[i][1] + bb[1];
        fx4 v2 = c[i][2] + bb[2], v3 = c[i][3] + bb[3];
        hx8 h0, h1;
        #pragma unroll
        for (int q = 0; q < 4; q++) {
            h0[q]     = (_Float16)fmaxf(v0[q], 0.f);
            h0[q + 4] = (_Float16)fmaxf(v1[q], 0.f);
            h1[q]     = (_Float16)fmaxf(v2[q], 0.f);
            h1[q + 4] = (_Float16)fmaxf(v3[q], 0.f);
        }
        *(hx8*)&H[(size_t)r * 256 + tx * 8]       = h0;
        *(hx8*)&H[(size_t)r * 256 + tx * 8 + 128] = h1;
    }
}

// gemm2 MFMA: Z[N,256] = fp16( H[N,256] @ W2 ), 128x128 tile, BK=64, dbuf LDS.
#define LDH 72
__global__ __launch_bounds__(256, 2) void k_gemm2m(const _Float16* __restrict__ A,
                                                   const _Float16* __restrict__ Bt,
                                                   _Float16* __restrict__ Z) {
    __shared__ __align__(16) _Float16 As[2][128 * LDH];
    __shared__ __align__(16) _Float16 Bs[2][128 * LDH];
    int tid = threadIdx.x;
    int lane = tid & 63, wid = tid >> 6;
    int wm = wid >> 1, wn = wid & 1;
    int row0 = blockIdx.x * 128, col0 = blockIdx.y * 128;
    int l15 = lane & 15, g = lane >> 4;
    int sr = tid >> 3, sc = tid & 7;

    fx4 acc[4][4];
    #pragma unroll
    for (int m = 0; m < 4; m++)
        #pragma unroll
        for (int n = 0; n < 4; n++) acc[m][n] = (fx4){0.f, 0.f, 0.f, 0.f};

    uint4 ga[4], gb[4];
    #pragma unroll
    for (int it = 0; it < 4; it++) {
        ga[it] = *(const uint4*)&A[(size_t)(row0 + sr + 32 * it) * 256 + sc * 8];
        gb[it] = *(const uint4*)&Bt[(size_t)(col0 + sr + 32 * it) * 256 + sc * 8];
    }
    #pragma unroll
    for (int it = 0; it < 4; it++) {
        *(uint4*)&As[0][(sr + 32 * it) * LDH + sc * 8] = ga[it];
        *(uint4*)&Bs[0][(sr + 32 * it) * LDH + sc * 8] = gb[it];
    }
    __syncthreads();

    int cur = 0;
    for (int t = 0; t < 4; t++) {
        if (t < 3) {
            int k0 = (t + 1) * 64;
            #pragma unroll
            for (int it = 0; it < 4; it++) {
                ga[it] = *(const uint4*)&A[(size_t)(row0 + sr + 32 * it) * 256 + k0 + sc * 8];
                gb[it] = *(const uint4*)&Bt[(size_t)(col0 + sr + 32 * it) * 256 + k0 + sc * 8];
            }
        }
        const _Float16* ap = As[cur];
        const _Float16* bp = Bs[cur];
        hx8 af[4][2], bf[4][2];
        #pragma unroll
        for (int m = 0; m < 4; m++)
            #pragma unroll
            for (int ks = 0; ks < 2; ks++)
                af[m][ks] = *(const hx8*)&ap[(wm * 64 + m * 16 + l15) * LDH + ks * 32 + g * 8];
        #pragma unroll
        for (int n = 0; n < 4; n++)
            #pragma unroll
            for (int ks = 0; ks < 2; ks++)
                bf[n][ks] = *(const hx8*)&bp[(wn * 64 + n * 16 + l15) * LDH + ks * 32 + g * 8];
        #pragma unroll
        for (int m = 0; m < 4; m++)
            #pragma unroll
            for (int n = 0; n < 4; n++) {
                acc[m][n] = __builtin_amdgcn_mfma_f32_16x16x32_f16(af[m][0], bf[n][0], acc[m][n], 0, 0, 0);
                acc[m][n] = __builtin_amdgcn_mfma_f32_16x16x32_f16(af[m][1], bf[n][1], acc[m][n], 0, 0, 0);
            }
        if (t < 3) {
            #pragma unroll
            for (int it = 0; it < 4; it++) {
                *(uint4*)&As[cur ^ 1][(sr + 32 * it) * LDH + sc * 8] = ga[it];
                *(uint4*)&Bs[cur ^ 1][(sr + 32 * it) * LDH + sc * 8] = gb[it];
            }
        }
        __syncthreads();
        cur ^= 1;
    }

    #pragma unroll
    for (int m = 0; m < 4; m++)
        #pragma unroll
        for (int n = 0; n < 4; n++) {
            int cc = col0 + wn * 64 + n * 16 + l15;
            #pragma unroll
            for (int r = 0; r < 4; r++) {
                int rr = row0 + wm * 64 + m * 16 + g * 4 + r;
                Z[(size_t)rr * 256 + cc] = (_Float16)acc[m][n][r];
            }
        }
}

// out[n,:] = relu( sum_e Z[src_e,:]*norm_e + bias ); Z fp16 [N][256].
__global__ __launch_bounds__(256) void k_aggb(const _Float16* __restrict__ Z, const int* __restrict__ indptr,
                                              const int* __restrict__ csrc, const float* __restrict__ cnorm,
                                              const float* __restrict__ bias, float* __restrict__ outb) {
    int lane = threadIdx.x & 63;
    int n = blockIdx.x * 4 + (threadIdx.x >> 6);
    int beg = indptr[n], end = indptr[n + 1];
    fx4 acc = (fx4){0.f, 0.f, 0.f, 0.f};
    int e = beg;
    for (; e + 1 < end; e += 2) {
        int s0 = csrc[e], s1 = csrc[e + 1];
        float n0 = cnorm[e], n1 = cnorm[e + 1];
        hx4 v0 = *(const hx4*)&Z[(size_t)s0 * 256 + lane * 4];
        hx4 v1 = *(const hx4*)&Z[(size_t)s1 * 256 + lane * 4];
        acc.x = fmaf((float)v0.x, n0, acc.x);
        acc.y = fmaf((float)v0.y, n0, acc.y);
        acc.z = fmaf((float)v0.z, n0, acc.z);
        acc.w = fmaf((float)v0.w, n0, acc.w);
        acc.x = fmaf((float)v1.x, n1, acc.x);
        acc.y = fmaf((float)v1.y, n1, acc.y);
        acc.z = fmaf((float)v1.z, n1, acc.z);
        acc.w = fmaf((float)v1.w, n1, acc.w);
    }
    if (e < end) {
        int s0 = csrc[e]; float n0 = cnorm[e];
        hx4 v0 = *(const hx4*)&Z[(size_t)s0 * 256 + lane * 4];
        acc.x = fmaf((float)v0.x, n0, acc.x);
        acc.y = fmaf((float)v0.y, n0, acc.y);
        acc.z = fmaf((float)v0.z, n0, acc.z);
        acc.w = fmaf((float)v0.w, n0, acc.w);
    }
    fx4 bb = *(const fx4*)&bias[lane * 4];
    acc += bb;
    acc.x = fmaxf(acc.x, 0.f); acc.y = fmaxf(acc.y, 0.f);
    acc.z = fmaxf(acc.z, 0.f); acc.w = fmaxf(acc.w, 0.f);
    *(fx4*)&outb[(size_t)n * 256 + lane * 4] = acc;
}

__global__ __launch_bounds__(256) void k_mean(const float* __restrict__ hb, float* __restrict__ pooled) {
    int b = blockIdx.x >> 2, q = blockIdx.x & 3;
    int h = threadIdx.x;
    const float* p = hb + ((size_t)(b * T2 + q * 128)) * 256 + h;
    float s = 0.f;
    #pragma unroll 4
    for (int t = 0; t < 128; t++) s += p[(size_t)t * 256];
    atomicAdd(&pooled[b * HID + h], s * (1.f / 512.f));
}

__global__ __launch_bounds__(64) void k_cls(const float* __restrict__ pooled, const float* __restrict__ cw,
                                            const float* __restrict__ cb, float* __restrict__ outp) {
    int b = blockIdx.x, lane = threadIdx.x;
    float po[10];
    #pragma unroll
    for (int o = 0; o < 10; o++) po[o] = 0.f;
    #pragma unroll
    for (int m = 0; m < 4; m++) {
        int hh = lane + m * 64;
        float ph = pooled[b * HID + hh];
        #pragma unroll
        for (int o = 0; o < 10; o++) po[o] = fmaf(ph, cw[hh * 10 + o], po[o]);
    }
    #pragma unroll
    for (int off = 32; off >= 1; off >>= 1) {
        #pragma unroll
        for (int o = 0; o < 10; o++) po[o] += __shfl_down(po[o], off);
    }
    if (lane == 0) {
        #pragma unroll
        for (int o = 0; o < 10; o++) outp[b * 10 + o] = po[o] + cb[o];
    }
}

extern "C" void kernel_launch(void* const* d_in, const int* in_sizes, int n_in,
                              void* d_out, int out_size, void* d_ws, size_t ws_size,
                              hipStream_t stream) {
    const float* x   = (const float*)d_in[0];
    const int*   ei  = (const int*)d_in[1];
    const float* w1  = (const float*)d_in[2];
    const float* b1  = (const float*)d_in[3];
    const float* w2  = (const float*)d_in[4];
    const float* b2  = (const float*)d_in[5];
    const float* g1w = (const float*)d_in[6];
    const float* g1b = (const float*)d_in[7];
    const float* g2w = (const float*)d_in[8];
    const float* g2b = (const float*)d_in[9];
    const float* cw  = (const float*)d_in[10];
    const float* cb  = (const float*)d_in[11];
    float* out = (float*)d_out;
    char* ws = (char*)d_ws;

    _Float16*       H      = (_Float16*)(ws + OFF_H);
    float*          H2     = (float*)(ws + OFF_H);     // reuses H region after gemm2
    _Float16*       Z      = (_Float16*)(ws + OFF_Z);
    float*          h1     = (float*)(ws + OFF_H1);
    float*          xn     = (float*)(ws + OFF_XN);
    float*          y1     = (float*)(ws + OFF_Y1);
    int*            deg    = (int*)(ws + OFF_DEG);
    int*            indptr = (int*)(ws + OFF_INDPTR);
    int*            cnt    = (int*)(ws + OFF_CNT);
    float*          dinv   = (float*)(ws + OFF_DINV);
    int*            csrc   = (int*)(ws + OFF_CSRC);
    float*          cnorm  = (float*)(ws + OFF_CNORM);
    float*          wt1    = (float*)(ws + OFF_WT1);
    float*          wt2    = (float*)(ws + OFF_WT2);
    float*          pooled = (float*)(ws + OFF_POOL);
    _Float16*       w2t    = (_Float16*)(ws + OFF_W2T);

    k_setup<<<174, 256, 0, stream>>>(deg, cnt, pooled, w1, w2, wt1, wt2, g2w, w2t);
    k_count<<<2048, 256, 0, stream>>>(ei, deg);
    k_conv1<<<dim3(8, 64), 256, 0, stream>>>(x, wt1, b1, h1);
    k_scan <<<1, 1024, 0, stream>>>(deg, indptr, dinv);
    k_fill <<<2176, 256, 0, stream>>>(ei, dinv, indptr, cnt, csrc, cnorm);
    k_conv2<<<dim3(4, 64), 256, 0, stream>>>(h1, wt2, b2, xn);
    k_agg32<<<8192, 256, 0, stream>>>(xn, indptr, csrc, cnorm, y1);          // y1 = A^ . X (32-wide)
    k_gemm1<<<512, 256, 0, stream>>>(y1, g1w, g1b, H);                       // H = fp16(relu(y1@W1+b1))
    k_gemm2m<<<dim3(256, 2), 256, 0, stream>>>(H, w2t, Z);                   // Z = fp16(H@W2)
    k_aggb <<<8192, 256, 0, stream>>>(Z, indptr, csrc, cnorm, g2b, H2);      // H2 = relu(A^ . Z + b2)
    k_mean <<<256, 256, 0, stream>>>(H2, pooled);
    k_cls  <<<64, 64, 0, stream>>>(pooled, cw, cb, out);
}

// Round 6
// 206.802 us; speedup vs baseline: 1.9582x; 1.1115x over previous
//
#include <hip/hip_runtime.h>

#define B_ 64
#define CIN 64
#define T_ 2048
#define C1 16
#define T1 1024
#define C2 32
#define T2 512
#define NN 32768
#define HID 256
#define OUTD 10
#define NE 524288
#define NTOT (NE + NN)

typedef __attribute__((ext_vector_type(4))) float fx4;
typedef __attribute__((ext_vector_type(2))) float fx2;
typedef __attribute__((ext_vector_type(8))) _Float16 hx8;
typedef __attribute__((ext_vector_type(4))) _Float16 hx4;

// ---- workspace byte offsets ----
#define OFF_H      (0ull)                    // 16 MB: H fp16 [N][256]
#define OFF_Z      (32ull<<20)               // 16 MB: gemm2 out, fp16 [N][256]
#define OFF_H1     (48ull<<20)               // 4 MB: conv1 out
#define OFF_XN     (52ull<<20)               // 4 MB: node features [N][32]
#define OFF_Y1     (56ull<<20)               // 4 MB: agg1 out [N][32]
#define OFF_DEG    (60ull<<20)               // 128 KB int
#define OFF_INDPTR ((60ull<<20) + (256u<<10))
#define OFF_CNT    ((60ull<<20) + (512u<<10))
#define OFF_DINV   ((60ull<<20) + (768u<<10))
#define OFF_CSRC   (61ull<<20)               // padded CSR src, cap 3.25 MB
#define OFF_CNORM  ((61ull<<20) + (3328u<<10))  // padded CSR norm, cap 3.25 MB
#define OFF_WT1    ((61ull<<20) + (6656u<<10))  // 20 KB (ends 67.5 MB)
#define OFF_WT2    (OFF_WT1 + (64u<<10))
#define OFF_POOL   (OFF_WT1 + (128u<<10))
#define OFF_W2T    (OFF_WT1 + (256u<<10))    // 128 KB: W2^T fp16

__device__ __forceinline__ fx4 shfl_xor4(fx4 v, int m) {
    return (fx4){__shfl_xor(v.x, m), __shfl_xor(v.y, m), __shfl_xor(v.z, m), __shfl_xor(v.w, m)};
}

// setup: blocks 0..127 init deg/cnt/pooled; 128..143 cvtw (W2->W2T fp16);
// 144..173 twt (conv weight transpose)
__global__ __launch_bounds__(256) void k_setup(int* deg, int* cnt, float* pooled,
                                               const float* __restrict__ w1, const float* __restrict__ w2,
                                               float* __restrict__ wt1, float* __restrict__ wt2,
                                               const float* __restrict__ gw2, _Float16* __restrict__ w2t) {
    __shared__ float tl[64][65];
    int blk = blockIdx.x, t = threadIdx.x;
    if (blk < 128) {
        int i = blk * 256 + t;
        if (i < NN) { deg[i] = 1; cnt[i] = 0; }   // deg starts at 1 (self-loop)
        if (i < B_ * HID) pooled[i] = 0.f;
    } else if (blk < 144) {
        int bb = blk - 128;
        int bx = bb & 3, by = bb >> 2;            // k-tile, n-tile
        #pragma unroll
        for (int it = 0; it < 16; it++) {
            int idx = it * 256 + t;
            int r = idx >> 6, c = idx & 63;
            tl[r][c] = gw2[(size_t)(bx * 64 + r) * 256 + by * 64 + c];
        }
        __syncthreads();
        #pragma unroll
        for (int it = 0; it < 16; it++) {
            int idx = it * 256 + t;
            int r = idx >> 6, c = idx & 63;
            w2t[(size_t)(by * 64 + r) * 256 + bx * 64 + c] = (_Float16)tl[c][r];
        }
    } else {
        int i = (blk - 144) * 256 + t;
        if (i < 16 * 64 * 5) {
            int co = i & 15; int r = i >> 4; int k = r % 5; int ci = r / 5;
            wt1[i] = w1[(co * 64 + ci) * 5 + k];
        }
        int j = i - 16 * 64 * 5;
        if (j >= 0 && j < 32 * 16 * 5) {
            int co = j & 31; int r = j >> 5; int k = r % 5; int ci = r / 5;
            wt2[j] = w2[(co * 16 + ci) * 5 + k];
        }
    }
}

__global__ __launch_bounds__(256) void k_count(const int* __restrict__ ei, int* __restrict__ deg) {
    int e = blockIdx.x * 256 + threadIdx.x;
    if (e < NE) atomicAdd(&deg[ei[NE + e]], 1);
}

// scan over PADDED degrees ((deg+7)&~7); also emits dinv = rsqrt(real deg)
__global__ __launch_bounds__(1024) void k_scan(const int* __restrict__ deg, int* __restrict__ indptr,
                                               float* __restrict__ dinv) {
    __shared__ int sd[1024];
    int tid = threadIdx.x;
    int base = tid * 32;
    int loc[32]; int s = 0;
    #pragma unroll
    for (int j = 0; j < 32; j++) {
        int d = deg[base + j];
        dinv[base + j] = rsqrtf((float)d);
        loc[j] = (d + 7) & ~7;
        s += loc[j];
    }
    sd[tid] = s; __syncthreads();
    for (int off = 1; off < 1024; off <<= 1) {
        int v = (tid >= off) ? sd[tid - off] : 0;
        __syncthreads();
        if (tid >= off) sd[tid] += v;
        __syncthreads();
    }
    int run = sd[tid] - s;
    #pragma unroll
    for (int j = 0; j < 32; j++) { indptr[base + j] = run; run += loc[j]; }
    if (tid == 1023) indptr[NN] = run;
}

// fill pad slots [deg, degp) with src=0, norm=0 (row 0 stays cached; contributes 0)
__global__ __launch_bounds__(256) void k_pad(const int* __restrict__ deg, const int* __restrict__ indptr,
                                             int* __restrict__ csrc, float* __restrict__ cnorm) {
    int n = blockIdx.x * 256 + threadIdx.x;
    if (n >= NN) return;
    int d = deg[n], dp = (d + 7) & ~7, base = indptr[n];
    for (int j = d; j < dp; j++) { csrc[base + j] = 0; cnorm[base + j] = 0.f; }
}

__global__ __launch_bounds__(256) void k_fill(const int* __restrict__ ei, const float* __restrict__ dinv,
                                              const int* __restrict__ indptr, int* __restrict__ cnt,
                                              int* __restrict__ csrc, float* __restrict__ cnorm) {
    int e = blockIdx.x * 256 + threadIdx.x;
    if (e >= NTOT) return;
    int s, d; float nrm;
    if (e < NE) { s = ei[e]; d = ei[NE + e]; nrm = dinv[s] * dinv[d]; }
    else        { s = d = e - NE;            nrm = dinv[s] * dinv[s]; }
    int pos = indptr[d] + atomicAdd(&cnt[d], 1);
    csrc[pos] = s; cnorm[pos] = nrm;
}

// conv1: x[64,64,2048] -> relu -> pool2 -> h1[64,16,1024]; single-phase staging
__global__ __launch_bounds__(256) void k_conv1(const float* __restrict__ x, const float* __restrict__ wt1,
                                               const float* __restrict__ b1, float* __restrict__ h1) {
    __shared__ float xs[64][260];
    __shared__ float ps[16][128];
    int tid = threadIdx.x;
    int tile = blockIdx.x;      // 0..7, 256 t each
    int b = blockIdx.y;
    int t0 = tile * 256;
    const float* xb = x + ((size_t)b * CIN) * T_ + t0;
    {   // interior cols 0..255 -> xs[r][2..257], 16 fx4 per thread
        int f = tid & 63, r0 = tid >> 6;
        #pragma unroll
        for (int it = 0; it < 16; it++) {
            int r = r0 + 4 * it;
            fx4 v = *(const fx4*)&xb[(size_t)r * T_ + f * 4];
            *(fx4*)&xs[r][2 + f * 4] = v;
        }
        // halo cols {-2,-1,256,257} -> xs[r][{0,1,258,259}], 1 per thread
        int r = tid >> 2, c = tid & 3;
        int off = (c < 2) ? (c - 2) : (254 + c);
        int gt = t0 + off;
        float v = 0.f;
        if (gt >= 0 && gt < T_) v = xb[(size_t)r * T_ + off];
        xs[r][2 + off] = v;
    }
    __syncthreads();
    float acc[16];
    #pragma unroll
    for (int i = 0; i < 16; i++) acc[i] = 0.f;
    for (int ci = 0; ci < 64; ci++) {
        float xv[5];
        #pragma unroll
        for (int j = 0; j < 5; j++) xv[j] = xs[ci][tid + j];
        const float* wp = wt1 + ci * 80;
        #pragma unroll
        for (int k = 0; k < 5; k++) {
            #pragma unroll
            for (int co = 0; co < 16; co++)
                acc[co] = fmaf(xv[k], wp[k * 16 + co], acc[co]);
        }
    }
    #pragma unroll
    for (int co = 0; co < 16; co++) {
        float a = fmaxf(acc[co] + b1[co], 0.f);
        float o = fmaxf(a, __shfl_xor(a, 1));
        if ((tid & 1) == 0) ps[co][tid >> 1] = o;
    }
    __syncthreads();
    for (int idx = tid; idx < 16 * 128; idx += 256) {
        int co = idx >> 7; int p = idx & 127;
        h1[(b * C1 + co) * T1 + tile * 128 + p] = ps[co][p];
    }
}

// conv2: h1[64,16,1024] -> relu -> pool2 -> xn[N,32] (node-major)
__global__ __launch_bounds__(256) void k_conv2(const float* __restrict__ h1, const float* __restrict__ wt2,
                                               const float* __restrict__ b2, float* __restrict__ xn) {
    __shared__ float xs[16][260];
    __shared__ float ps[128 * 32];
    int tid = threadIdx.x;
    int tile = blockIdx.x;      // 0..3
    int b = blockIdx.y;
    int t0 = tile * 256;
    float acc[32];
    #pragma unroll
    for (int i = 0; i < 32; i++) acc[i] = 0.f;
    for (int idx = tid; idx < 16 * 260; idx += 256) {
        int r = idx / 260, c = idx % 260;
        int gt = t0 + c - 2;
        float v = 0.f;
        if (gt >= 0 && gt < T1) v = h1[(b * C1 + r) * T1 + gt];
        xs[r][c] = v;
    }
    __syncthreads();
    for (int ci = 0; ci < 16; ci++) {
        float xv[5];
        #pragma unroll
        for (int j = 0; j < 5; j++) xv[j] = xs[ci][tid + j];
        const float* wp = wt2 + (ci * 5) * 32;
        #pragma unroll
        for (int k = 0; k < 5; k++) {
            #pragma unroll
            for (int co = 0; co < 32; co++)
                acc[co] = fmaf(xv[k], wp[k * 32 + co], acc[co]);
        }
    }
    #pragma unroll
    for (int co = 0; co < 32; co++) {
        float a = fmaxf(acc[co] + b2[co], 0.f);
        float o = fmaxf(a, __shfl_xor(a, 1));
        if ((tid & 1) == 0) ps[(tid >> 1) * 32 + co] = o;
    }
    __syncthreads();
    int base = (b * T2 + tile * 128) * 32;
    for (int idx = tid; idx < 128 * 32; idx += 256) xn[base + idx] = ps[idx];
}

// agg1: y1[n,:] = sum_e norm_e * xn[src_e,:]; 8 edge-slots x 8 lanes x fx4,
// branch-free (padded lists), unroll 2.
__global__ __launch_bounds__(256) void k_agg32(const float* __restrict__ xn, const int* __restrict__ indptr,
                                               const int* __restrict__ csrc, const float* __restrict__ cnorm,
                                               float* __restrict__ y1) {
    int lane = threadIdx.x & 63;
    int n = blockIdx.x * 4 + (threadIdx.x >> 6);
    int slot = lane >> 3, f4 = (lane & 7) * 4;
    int beg = indptr[n];
    int iter = (indptr[n + 1] - beg) >> 3;
    const int* cs = csrc + beg + slot;
    const float* cn = cnorm + beg + slot;
    fx4 acc = (fx4){0.f, 0.f, 0.f, 0.f};
    int i = 0;
    for (; i + 1 < iter; i += 2) {
        int s0 = cs[8 * i], s1 = cs[8 * i + 8];
        float m0 = cn[8 * i], m1 = cn[8 * i + 8];
        fx4 v0 = *(const fx4*)&xn[(size_t)s0 * 32 + f4];
        fx4 v1 = *(const fx4*)&xn[(size_t)s1 * 32 + f4];
        acc += v0 * m0;
        acc += v1 * m1;
    }
    if (i < iter) {
        int s0 = cs[8 * i]; float m0 = cn[8 * i];
        fx4 v0 = *(const fx4*)&xn[(size_t)s0 * 32 + f4];
        acc += v0 * m0;
    }
    acc += shfl_xor4(acc, 8);
    acc += shfl_xor4(acc, 16);
    acc += shfl_xor4(acc, 32);
    if (lane < 8) *(fx4*)&y1[(size_t)n * 32 + f4] = acc;
}

// gemm1: H[N,256] = fp16( relu(y1[N,32] @ W1[32,256] + b1) ); 64-row tiles.
__global__ __launch_bounds__(256) void k_gemm1(const float* __restrict__ A, const float* __restrict__ W,
                                               const float* __restrict__ bias, _Float16* __restrict__ H) {
    __shared__ __align__(16) float xT[32 * 68];   // [k][r], 64 rows + pad
    __shared__ __align__(16) float wl[32 * 256];
    int tid = threadIdx.x;
    int ty = tid >> 4, tx = tid & 15;
    int rows0 = blockIdx.x * 64;
    int kq = tid & 7, rs = tid >> 3;              // staging coords (rs 0..31)
    {
        fx4 v0 = *(const fx4*)&A[(size_t)(rows0 + rs) * 32 + kq * 4];
        fx4 v1 = *(const fx4*)&A[(size_t)(rows0 + rs + 32) * 32 + kq * 4];
        #pragma unroll
        for (int i = 0; i < 4; i++) {
            xT[(kq * 4 + i) * 68 + rs]      = v0[i];
            xT[(kq * 4 + i) * 68 + rs + 32] = v1[i];
        }
    }
    #pragma unroll
    for (int m = 0; m < 8; m++)
        *(fx4*)&wl[m * 1024 + tid * 4] = *(const fx4*)&W[(size_t)(m * 1024 + tid * 4)];
    __syncthreads();

    fx4 c[4][4];
    #pragma unroll
    for (int i = 0; i < 4; i++)
        #pragma unroll
        for (int j = 0; j < 4; j++) c[i][j] = (fx4){0.f, 0.f, 0.f, 0.f};

    #pragma unroll 8
    for (int kk = 0; kk < 32; kk++) {
        fx4 xa = *(const fx4*)&xT[kk * 68 + ty * 4];
        fx4 w[4];
        w[0] = *(const fx4*)&wl[kk * 256 + tx * 8];
        w[1] = *(const fx4*)&wl[kk * 256 + tx * 8 + 4];
        w[2] = *(const fx4*)&wl[kk * 256 + tx * 8 + 128];
        w[3] = *(const fx4*)&wl[kk * 256 + tx * 8 + 132];
        #pragma unroll
        for (int j = 0; j < 4; j++) {
            c[0][j] += xa.x * w[j];
            c[1][j] += xa.y * w[j];
            c[2][j] += xa.z * w[j];
            c[3][j] += xa.w * w[j];
        }
    }
    fx4 bb[4];
    bb[0] = *(const fx4*)&bias[tx * 8];
    bb[1] = *(const fx4*)&bias[tx * 8 + 4];
    bb[2] = *(const fx4*)&bias[tx * 8 + 128];
    bb[3] = *(const fx4*)&bias[tx * 8 + 132];
    #pragma unroll
    for (int i = 0; i < 4; i++) {
        int r = rows0 + ty * 4 + i;
        fx4 v0 = c[i][0] + bb[0], v1 = c[i][1] + bb[1];
        fx4 v2 = c[i][2] + bb[2], v3 = c[i][3] + bb[3];
        hx8 h0, h1;
        #pragma unroll
        for (int q = 0; q < 4; q++) {
            h0[q]     = (_Float16)fmaxf(v0[q], 0.f);
            h0[q + 4] = (_Float16)fmaxf(v1[q], 0.f);
            h1[q]     = (_Float16)fmaxf(v2[q], 0.f);
            h1[q + 4] = (_Float16)fmaxf(v3[q], 0.f);
        }
        *(hx8*)&H[(size_t)r * 256 + tx * 8]       = h0;
        *(hx8*)&H[(size_t)r * 256 + tx * 8 + 128] = h1;
    }
}

// gemm2 MFMA: Z[N,256] = fp16( H[N,256] @ W2 ), 128x128 tile, BK=64, dbuf LDS.
#define LDH 72
__global__ __launch_bounds__(256, 2) void k_gemm2m(const _Float16* __restrict__ A,
                                                   const _Float16* __restrict__ Bt,
                                                   _Float16* __restrict__ Z) {
    __shared__ __align__(16) _Float16 As[2][128 * LDH];
    __shared__ __align__(16) _Float16 Bs[2][128 * LDH];
    int tid = threadIdx.x;
    int lane = tid & 63, wid = tid >> 6;
    int wm = wid >> 1, wn = wid & 1;
    int row0 = blockIdx.x * 128, col0 = blockIdx.y * 128;
    int l15 = lane & 15, g = lane >> 4;
    int sr = tid >> 3, sc = tid & 7;

    fx4 acc[4][4];
    #pragma unroll
    for (int m = 0; m < 4; m++)
        #pragma unroll
        for (int n = 0; n < 4; n++) acc[m][n] = (fx4){0.f, 0.f, 0.f, 0.f};

    uint4 ga[4], gb[4];
    #pragma unroll
    for (int it = 0; it < 4; it++) {
        ga[it] = *(const uint4*)&A[(size_t)(row0 + sr + 32 * it) * 256 + sc * 8];
        gb[it] = *(const uint4*)&Bt[(size_t)(col0 + sr + 32 * it) * 256 + sc * 8];
    }
    #pragma unroll
    for (int it = 0; it < 4; it++) {
        *(uint4*)&As[0][(sr + 32 * it) * LDH + sc * 8] = ga[it];
        *(uint4*)&Bs[0][(sr + 32 * it) * LDH + sc * 8] = gb[it];
    }
    __syncthreads();

    int cur = 0;
    for (int t = 0; t < 4; t++) {
        if (t < 3) {
            int k0 = (t + 1) * 64;
            #pragma unroll
            for (int it = 0; it < 4; it++) {
                ga[it] = *(const uint4*)&A[(size_t)(row0 + sr + 32 * it) * 256 + k0 + sc * 8];
                gb[it] = *(const uint4*)&Bt[(size_t)(col0 + sr + 32 * it) * 256 + k0 + sc * 8];
            }
        }
        const _Float16* ap = As[cur];
        const _Float16* bp = Bs[cur];
        hx8 af[4][2], bf[4][2];
        #pragma unroll
        for (int m = 0; m < 4; m++)
            #pragma unroll
            for (int ks = 0; ks < 2; ks++)
                af[m][ks] = *(const hx8*)&ap[(wm * 64 + m * 16 + l15) * LDH + ks * 32 + g * 8];
        #pragma unroll
        for (int n = 0; n < 4; n++)
            #pragma unroll
            for (int ks = 0; ks < 2; ks++)
                bf[n][ks] = *(const hx8*)&bp[(wn * 64 + n * 16 + l15) * LDH + ks * 32 + g * 8];
        #pragma unroll
        for (int m = 0; m < 4; m++)
            #pragma unroll
            for (int n = 0; n < 4; n++) {
                acc[m][n] = __builtin_amdgcn_mfma_f32_16x16x32_f16(af[m][0], bf[n][0], acc[m][n], 0, 0, 0);
                acc[m][n] = __builtin_amdgcn_mfma_f32_16x16x32_f16(af[m][1], bf[n][1], acc[m][n], 0, 0, 0);
            }
        if (t < 3) {
            #pragma unroll
            for (int it = 0; it < 4; it++) {
                *(uint4*)&As[cur ^ 1][(sr + 32 * it) * LDH + sc * 8] = ga[it];
                *(uint4*)&Bs[cur ^ 1][(sr + 32 * it) * LDH + sc * 8] = gb[it];
            }
        }
        __syncthreads();
        cur ^= 1;
    }

    #pragma unroll
    for (int m = 0; m < 4; m++)
        #pragma unroll
        for (int n = 0; n < 4; n++) {
            int cc = col0 + wn * 64 + n * 16 + l15;
            #pragma unroll
            for (int r = 0; r < 4; r++) {
                int rr = row0 + wm * 64 + m * 16 + g * 4 + r;
                Z[(size_t)rr * 256 + cc] = (_Float16)acc[m][n][r];
            }
        }
}

#define ACC8(v, m) \
    a0.x = fmaf((float)v[0], m, a0.x); a0.y = fmaf((float)v[1], m, a0.y); \
    a0.z = fmaf((float)v[2], m, a0.z); a0.w = fmaf((float)v[3], m, a0.w); \
    a1.x = fmaf((float)v[4], m, a1.x); a1.y = fmaf((float)v[5], m, a1.y); \
    a1.z = fmaf((float)v[6], m, a1.z); a1.w = fmaf((float)v[7], m, a1.w);

// agg2 + mean fused: per node n, h2 = relu(sum_e Z[src,:]*norm + b2); block
// (4 nodes) LDS-reduces and atomically adds h2/512 into pooled[b,:].
// Half-wave per edge (32 lanes x 16 B), unroll 4 -> 8 rows (4 KB) in flight/wave.
__global__ __launch_bounds__(256) void k_aggm(const _Float16* __restrict__ Z, const int* __restrict__ indptr,
                                              const int* __restrict__ csrc, const float* __restrict__ cnorm,
                                              const float* __restrict__ bias, float* __restrict__ pooled) {
    __shared__ float ps[4][256];
    int tid = threadIdx.x;
    int wid = tid >> 6, lane = tid & 63;
    int h = lane >> 5, fl = lane & 31;
    int n = blockIdx.x * 4 + wid;
    int beg = indptr[n];
    int half = (indptr[n + 1] - beg) >> 1;   // multiple of 4 (padded lists)
    const int* cs = csrc + beg + h;
    const float* cn = cnorm + beg + h;
    fx4 a0 = (fx4){0.f, 0.f, 0.f, 0.f};
    fx4 a1 = (fx4){0.f, 0.f, 0.f, 0.f};
    for (int i = 0; i < half; i += 4) {
        int s0 = cs[2 * i], s1 = cs[2 * i + 2], s2 = cs[2 * i + 4], s3 = cs[2 * i + 6];
        float m0 = cn[2 * i], m1 = cn[2 * i + 2], m2 = cn[2 * i + 4], m3 = cn[2 * i + 6];
        hx8 v0 = *(const hx8*)&Z[(size_t)s0 * 256 + fl * 8];
        hx8 v1 = *(const hx8*)&Z[(size_t)s1 * 256 + fl * 8];
        hx8 v2 = *(const hx8*)&Z[(size_t)s2 * 256 + fl * 8];
        hx8 v3 = *(const hx8*)&Z[(size_t)s3 * 256 + fl * 8];
        ACC8(v0, m0)
        ACC8(v1, m1)
        ACC8(v2, m2)
        ACC8(v3, m3)
    }
    a0 += shfl_xor4(a0, 32);
    a1 += shfl_xor4(a1, 32);
    fx4 b0 = *(const fx4*)&bias[fl * 8];
    fx4 b1 = *(const fx4*)&bias[fl * 8 + 4];
    a0 += b0; a1 += b1;
    a0.x = fmaxf(a0.x, 0.f); a0.y = fmaxf(a0.y, 0.f);
    a0.z = fmaxf(a0.z, 0.f); a0.w = fmaxf(a0.w, 0.f);
    a1.x = fmaxf(a1.x, 0.f); a1.y = fmaxf(a1.y, 0.f);
    a1.z = fmaxf(a1.z, 0.f); a1.w = fmaxf(a1.w, 0.f);
    if (h == 0) {
        *(fx4*)&ps[wid][fl * 8]     = a0;
        *(fx4*)&ps[wid][fl * 8 + 4] = a1;
    }
    __syncthreads();
    float s = ps[0][tid] + ps[1][tid] + ps[2][tid] + ps[3][tid];
    atomicAdd(&pooled[(blockIdx.x >> 7) * 256 + tid], s * (1.f / 512.f));
}

__global__ __launch_bounds__(64) void k_cls(const float* __restrict__ pooled, const float* __restrict__ cw,
                                            const float* __restrict__ cb, float* __restrict__ outp) {
    int b = blockIdx.x, lane = threadIdx.x;
    float po[10];
    #pragma unroll
    for (int o = 0; o < 10; o++) po[o] = 0.f;
    #pragma unroll
    for (int m = 0; m < 4; m++) {
        int hh = lane + m * 64;
        float ph = pooled[b * HID + hh];
        #pragma unroll
        for (int o = 0; o < 10; o++) po[o] = fmaf(ph, cw[hh * 10 + o], po[o]);
    }
    #pragma unroll
    for (int off = 32; off >= 1; off >>= 1) {
        #pragma unroll
        for (int o = 0; o < 10; o++) po[o] += __shfl_down(po[o], off);
    }
    if (lane == 0) {
        #pragma unroll
        for (int o = 0; o < 10; o++) outp[b * 10 + o] = po[o] + cb[o];
    }
}

extern "C" void kernel_launch(void* const* d_in, const int* in_sizes, int n_in,
                              void* d_out, int out_size, void* d_ws, size_t ws_size,
                              hipStream_t stream) {
    const float* x   = (const float*)d_in[0];
    const int*   ei  = (const int*)d_in[1];
    const float* w1  = (const float*)d_in[2];
    const float* b1  = (const float*)d_in[3];
    const float* w2  = (const float*)d_in[4];
    const float* b2  = (const float*)d_in[5];
    const float* g1w = (const float*)d_in[6];
    const float* g1b = (const float*)d_in[7];
    const float* g2w = (const float*)d_in[8];
    const float* g2b = (const float*)d_in[9];
    const float* cw  = (const float*)d_in[10];
    const float* cb  = (const float*)d_in[11];
    float* out = (float*)d_out;
    char* ws = (char*)d_ws;

    _Float16*       H      = (_Float16*)(ws + OFF_H);
    _Float16*       Z      = (_Float16*)(ws + OFF_Z);
    float*          h1     = (float*)(ws + OFF_H1);
    float*          xn     = (float*)(ws + OFF_XN);
    float*          y1     = (float*)(ws + OFF_Y1);
    int*            deg    = (int*)(ws + OFF_DEG);
    int*            indptr = (int*)(ws + OFF_INDPTR);
    int*            cnt    = (int*)(ws + OFF_CNT);
    float*          dinv   = (float*)(ws + OFF_DINV);
    int*            csrc   = (int*)(ws + OFF_CSRC);
    float*          cnorm  = (float*)(ws + OFF_CNORM);
    float*          wt1    = (float*)(ws + OFF_WT1);
    float*          wt2    = (float*)(ws + OFF_WT2);
    float*          pooled = (float*)(ws + OFF_POOL);
    _Float16*       w2t    = (_Float16*)(ws + OFF_W2T);

    k_setup<<<174, 256, 0, stream>>>(deg, cnt, pooled, w1, w2, wt1, wt2, g2w, w2t);
    k_count<<<2048, 256, 0, stream>>>(ei, deg);
    k_conv1<<<dim3(8, 64), 256, 0, stream>>>(x, wt1, b1, h1);
    k_scan <<<1, 1024, 0, stream>>>(deg, indptr, dinv);
    k_pad  <<<128, 256, 0, stream>>>(deg, indptr, csrc, cnorm);
    k_fill <<<2176, 256, 0, stream>>>(ei, dinv, indptr, cnt, csrc, cnorm);
    k_conv2<<<dim3(4, 64), 256, 0, stream>>>(h1, wt2, b2, xn);
    k_agg32<<<8192, 256, 0, stream>>>(xn, indptr, csrc, cnorm, y1);          // y1 = A^ . X (32-wide)
    k_gemm1<<<512, 256, 0, stream>>>(y1, g1w, g1b, H);                       // H = fp16(relu(y1@W1+b1))
    k_gemm2m<<<dim3(256, 2), 256, 0, stream>>>(H, w2t, Z);                   // Z = fp16(H@W2)
    k_aggm <<<8192, 256, 0, stream>>>(Z, indptr, csrc, cnorm, g2b, pooled);  // pooled += relu(A^ . Z + b2)/512
    k_cls  <<<64, 64, 0, stream>>>(pooled, cw, cb, out);
}

// Round 7
// 202.356 us; speedup vs baseline: 2.0013x; 1.0220x over previous
//
#include <hip/hip_runtime.h>

#define B_ 64
#define CIN 64
#define T_ 2048
#define C1 16
#define T1 1024
#define C2 32
#define T2 512
#define NN 32768
#define HID 256
#define OUTD 10
#define NE 524288
#define NTOT (NE + NN)          // 557056 = 2176*256 exactly

typedef __attribute__((ext_vector_type(4))) float fx4;
typedef __attribute__((ext_vector_type(8))) _Float16 hx8;
typedef __attribute__((ext_vector_type(4))) _Float16 hx4;

// ---- workspace byte offsets (ends ~51.5 MB; ws proven >= 75 MB) ----
#define OFF_H      (0ull)                    // 16 MB: H fp16 [N][256]
#define OFF_Z      (16ull<<20)               // 16 MB + 64K: Z fp16 [N+1][256] (row NN = zero dummy)
#define OFF_H1     (33ull<<20)               // 4 MB: conv1 out
#define OFF_XN     (37ull<<20)               // 4 MB + 64K: xn [N+1][32] (row NN = zero dummy)
#define OFF_Y1     (42ull<<20)               // 4 MB: agg1 out [N][32]
#define OFF_DEG    (46ull<<20)               // 128 KB int
#define OFF_INDPTR ((46ull<<20) + (256u<<10))
#define OFF_CNT    ((46ull<<20) + (512u<<10))
#define OFF_DINV   ((46ull<<20) + (768u<<10))   // [N+1] floats
#define OFF_CSRC   (47ull<<20)               // padded CSR src, cap 3.25 MB
#define OFF_WT1    (51ull<<20)               // 20 KB
#define OFF_WT2    (OFF_WT1 + (64u<<10))
#define OFF_POOL   (OFF_WT1 + (128u<<10))
#define OFF_W2T    (OFF_WT1 + (256u<<10))    // 128 KB: W2^T fp16

__device__ __forceinline__ fx4 shfl_xor4(fx4 v, int m) {
    return (fx4){__shfl_xor(v.x, m), __shfl_xor(v.y, m), __shfl_xor(v.z, m), __shfl_xor(v.w, m)};
}

// setup: blocks 0..127 init deg/cnt/pooled (+zero dummy rows of xn, Z);
// 128..143 cvtw (W2->W2T fp16); 144..173 twt (conv weight transpose)
__global__ __launch_bounds__(256) void k_setup(int* deg, int* cnt, float* pooled,
                                               const float* __restrict__ w1, const float* __restrict__ w2,
                                               float* __restrict__ wt1, float* __restrict__ wt2,
                                               const float* __restrict__ gw2, _Float16* __restrict__ w2t,
                                               float* __restrict__ xnz, unsigned* __restrict__ zz) {
    __shared__ float tl[64][65];
    int blk = blockIdx.x, t = threadIdx.x;
    if (blk < 128) {
        int i = blk * 256 + t;
        if (i < NN) { deg[i] = 1; cnt[i] = 0; }   // deg starts at 1 (self-loop)
        if (i < B_ * HID) pooled[i] = 0.f;
        if (blk == 0 && t < 32) xnz[t] = 0.f;     // xn dummy row NN
        if (blk == 1 && t < 128) zz[t] = 0u;      // Z dummy row NN (512 B)
    } else if (blk < 144) {
        int bb = blk - 128;
        int bx = bb & 3, by = bb >> 2;            // k-tile, n-tile
        #pragma unroll
        for (int it = 0; it < 16; it++) {
            int idx = it * 256 + t;
            int r = idx >> 6, c = idx & 63;
            tl[r][c] = gw2[(size_t)(bx * 64 + r) * 256 + by * 64 + c];
        }
        __syncthreads();
        #pragma unroll
        for (int it = 0; it < 16; it++) {
            int idx = it * 256 + t;
            int r = idx >> 6, c = idx & 63;
            w2t[(size_t)(by * 64 + r) * 256 + bx * 64 + c] = (_Float16)tl[c][r];
        }
    } else {
        int i = (blk - 144) * 256 + t;
        if (i < 16 * 64 * 5) {
            int co = i & 15; int r = i >> 4; int k = r % 5; int ci = r / 5;
            wt1[i] = w1[(co * 64 + ci) * 5 + k];
        }
        int j = i - 16 * 64 * 5;
        if (j >= 0 && j < 32 * 16 * 5) {
            int co = j & 31; int r = j >> 5; int k = r % 5; int ci = r / 5;
            wt2[j] = w2[(co * 16 + ci) * 5 + k];
        }
    }
}

__global__ __launch_bounds__(256) void k_count(const int* __restrict__ ei, int* __restrict__ deg) {
    int e = blockIdx.x * 256 + threadIdx.x;
    if (e < NE) atomicAdd(&deg[ei[NE + e]], 1);
}

// scan over PADDED degrees ((deg+7)&~7); emits dinv = rsqrt(real deg), dinv[NN]=0
__global__ __launch_bounds__(1024) void k_scan(const int* __restrict__ deg, int* __restrict__ indptr,
                                               float* __restrict__ dinv) {
    __shared__ int sd[1024];
    int tid = threadIdx.x;
    int base = tid * 32;
    int loc[32]; int s = 0;
    #pragma unroll
    for (int j = 0; j < 32; j++) {
        int d = deg[base + j];
        dinv[base + j] = rsqrtf((float)d);
        loc[j] = d;
        s += (d + 7) & ~7;
    }
    sd[tid] = s; __syncthreads();
    for (int off = 1; off < 1024; off <<= 1) {
        int v = (tid >= off) ? sd[tid - off] : 0;
        __syncthreads();
        if (tid >= off) sd[tid] += v;
        __syncthreads();
    }
    int run = sd[tid] - s;
    #pragma unroll
    for (int j = 0; j < 32; j++) { indptr[base + j] = run; run += (loc[j] + 7) & ~7; }
    if (tid == 1023) { indptr[NN] = run; dinv[NN] = 0.f; }
}

// fill: blocks <2176 scatter src per edge (single 4 B store); blocks >=2176
// write pad sentinels (src=NN) into slots [deg, degp).
__global__ __launch_bounds__(256) void k_fill(const int* __restrict__ ei, const int* __restrict__ deg,
                                              const int* __restrict__ indptr, int* __restrict__ cnt,
                                              int* __restrict__ csrc) {
    int idx = blockIdx.x * 256 + threadIdx.x;
    if (idx < NTOT) {
        int s, d;
        if (idx < NE) { s = ei[idx]; d = ei[NE + idx]; }
        else          { s = d = idx - NE; }
        int pos = indptr[d] + atomicAdd(&cnt[d], 1);
        csrc[pos] = s;
    } else {
        int n = idx - NTOT;
        if (n < NN) {
            int dd = deg[n], dp = (dd + 7) & ~7, base = indptr[n];
            for (int j = dd; j < dp; j++) csrc[base + j] = NN;
        }
    }
}

// conv1: x[64,64,2048] -> relu -> pool2 -> h1[64,16,1024]; single-phase staging
__global__ __launch_bounds__(256) void k_conv1(const float* __restrict__ x, const float* __restrict__ wt1,
                                               const float* __restrict__ b1, float* __restrict__ h1) {
    __shared__ float xs[64][260];
    __shared__ float ps[16][128];
    int tid = threadIdx.x;
    int tile = blockIdx.x;      // 0..7, 256 t each
    int b = blockIdx.y;
    int t0 = tile * 256;
    const float* xb = x + ((size_t)b * CIN) * T_ + t0;
    {   // interior cols 0..255 -> xs[r][2..257], 16 fx4 per thread
        int f = tid & 63, r0 = tid >> 6;
        #pragma unroll
        for (int it = 0; it < 16; it++) {
            int r = r0 + 4 * it;
            fx4 v = *(const fx4*)&xb[(size_t)r * T_ + f * 4];
            *(fx4*)&xs[r][2 + f * 4] = v;
        }
        // halo cols {-2,-1,256,257} -> xs[r][{0,1,258,259}], 1 per thread
        int r = tid >> 2, c = tid & 3;
        int off = (c < 2) ? (c - 2) : (254 + c);
        int gt = t0 + off;
        float v = 0.f;
        if (gt >= 0 && gt < T_) v = xb[(size_t)r * T_ + off];
        xs[r][2 + off] = v;
    }
    __syncthreads();
    float acc[16];
    #pragma unroll
    for (int i = 0; i < 16; i++) acc[i] = 0.f;
    for (int ci = 0; ci < 64; ci++) {
        float xv[5];
        #pragma unroll
        for (int j = 0; j < 5; j++) xv[j] = xs[ci][tid + j];
        const float* wp = wt1 + ci * 80;
        #pragma unroll
        for (int k = 0; k < 5; k++) {
            #pragma unroll
            for (int co = 0; co < 16; co++)
                acc[co] = fmaf(xv[k], wp[k * 16 + co], acc[co]);
        }
    }
    #pragma unroll
    for (int co = 0; co < 16; co++) {
        float a = fmaxf(acc[co] + b1[co], 0.f);
        float o = fmaxf(a, __shfl_xor(a, 1));
        if ((tid & 1) == 0) ps[co][tid >> 1] = o;
    }
    __syncthreads();
    for (int idx = tid; idx < 16 * 128; idx += 256) {
        int co = idx >> 7; int p = idx & 127;
        h1[(b * C1 + co) * T1 + tile * 128 + p] = ps[co][p];
    }
}

// conv2: h1[64,16,1024] -> relu -> pool2 -> xn[N,32] (node-major)
__global__ __launch_bounds__(256) void k_conv2(const float* __restrict__ h1, const float* __restrict__ wt2,
                                               const float* __restrict__ b2, float* __restrict__ xn) {
    __shared__ float xs[16][260];
    __shared__ float ps[128 * 32];
    int tid = threadIdx.x;
    int tile = blockIdx.x;      // 0..3
    int b = blockIdx.y;
    int t0 = tile * 256;
    float acc[32];
    #pragma unroll
    for (int i = 0; i < 32; i++) acc[i] = 0.f;
    for (int idx = tid; idx < 16 * 260; idx += 256) {
        int r = idx / 260, c = idx % 260;
        int gt = t0 + c - 2;
        float v = 0.f;
        if (gt >= 0 && gt < T1) v = h1[(b * C1 + r) * T1 + gt];
        xs[r][c] = v;
    }
    __syncthreads();
    for (int ci = 0; ci < 16; ci++) {
        float xv[5];
        #pragma unroll
        for (int j = 0; j < 5; j++) xv[j] = xs[ci][tid + j];
        const float* wp = wt2 + (ci * 5) * 32;
        #pragma unroll
        for (int k = 0; k < 5; k++) {
            #pragma unroll
            for (int co = 0; co < 32; co++)
                acc[co] = fmaf(xv[k], wp[k * 32 + co], acc[co]);
        }
    }
    #pragma unroll
    for (int co = 0; co < 32; co++) {
        float a = fmaxf(acc[co] + b2[co], 0.f);
        float o = fmaxf(a, __shfl_xor(a, 1));
        if ((tid & 1) == 0) ps[(tid >> 1) * 32 + co] = o;
    }
    __syncthreads();
    int base = (b * T2 + tile * 128) * 32;
    for (int idx = tid; idx < 128 * 32; idx += 256) xn[base + idx] = ps[idx];
}

// agg1: y1[n,:] = sum_e dinv[s]*dinv[n] * xn[s,:]; 8 edge-slots x 8 lanes x fx4,
// branch-free (padded lists; pad s=NN has dinv=0 and zero row).
__global__ __launch_bounds__(256) void k_agg32(const float* __restrict__ xn, const int* __restrict__ indptr,
                                               const int* __restrict__ csrc, const float* __restrict__ dinv,
                                               float* __restrict__ y1) {
    int lane = threadIdx.x & 63;
    int n = blockIdx.x * 4 + (threadIdx.x >> 6);
    int slot = lane >> 3, f4 = (lane & 7) * 4;
    int beg = indptr[n];
    int iter = (indptr[n + 1] - beg) >> 3;
    float dn = dinv[n];
    const int* cs = csrc + beg + slot;
    fx4 acc = (fx4){0.f, 0.f, 0.f, 0.f};
    int i = 0;
    for (; i + 1 < iter; i += 2) {
        int s0 = cs[8 * i], s1 = cs[8 * i + 8];
        float m0 = dinv[s0] * dn, m1 = dinv[s1] * dn;
        fx4 v0 = *(const fx4*)&xn[(size_t)s0 * 32 + f4];
        fx4 v1 = *(const fx4*)&xn[(size_t)s1 * 32 + f4];
        acc += v0 * m0;
        acc += v1 * m1;
    }
    if (i < iter) {
        int s0 = cs[8 * i];
        float m0 = dinv[s0] * dn;
        fx4 v0 = *(const fx4*)&xn[(size_t)s0 * 32 + f4];
        acc += v0 * m0;
    }
    acc += shfl_xor4(acc, 8);
    acc += shfl_xor4(acc, 16);
    acc += shfl_xor4(acc, 32);
    if (lane < 8) *(fx4*)&y1[(size_t)n * 32 + f4] = acc;
}

// gemm1: H[N,256] = fp16( relu(y1[N,32] @ W1[32,256] + b1) ); 64-row tiles.
__global__ __launch_bounds__(256) void k_gemm1(const float* __restrict__ A, const float* __restrict__ W,
                                               const float* __restrict__ bias, _Float16* __restrict__ H) {
    __shared__ __align__(16) float xT[32 * 68];   // [k][r], 64 rows + pad
    __shared__ __align__(16) float wl[32 * 256];
    int tid = threadIdx.x;
    int ty = tid >> 4, tx = tid & 15;
    int rows0 = blockIdx.x * 64;
    int kq = tid & 7, rs = tid >> 3;              // staging coords (rs 0..31)
    {
        fx4 v0 = *(const fx4*)&A[(size_t)(rows0 + rs) * 32 + kq * 4];
        fx4 v1 = *(const fx4*)&A[(size_t)(rows0 + rs + 32) * 32 + kq * 4];
        #pragma unroll
        for (int i = 0; i < 4; i++) {
            xT[(kq * 4 + i) * 68 + rs]      = v0[i];
            xT[(kq * 4 + i) * 68 + rs + 32] = v1[i];
        }
    }
    #pragma unroll
    for (int m = 0; m < 8; m++)
        *(fx4*)&wl[m * 1024 + tid * 4] = *(const fx4*)&W[(size_t)(m * 1024 + tid * 4)];
    __syncthreads();

    fx4 c[4][4];
    #pragma unroll
    for (int i = 0; i < 4; i++)
        #pragma unroll
        for (int j = 0; j < 4; j++) c[i][j] = (fx4){0.f, 0.f, 0.f, 0.f};

    #pragma unroll 8
    for (int kk = 0; kk < 32; kk++) {
        fx4 xa = *(const fx4*)&xT[kk * 68 + ty * 4];
        fx4 w[4];
        w[0] = *(const fx4*)&wl[kk * 256 + tx * 8];
        w[1] = *(const fx4*)&wl[kk * 256 + tx * 8 + 4];
        w[2] = *(const fx4*)&wl[kk * 256 + tx * 8 + 128];
        w[3] = *(const fx4*)&wl[kk * 256 + tx * 8 + 132];
        #pragma unroll
        for (int j = 0; j < 4; j++) {
            c[0][j] += xa.x * w[j];
            c[1][j] += xa.y * w[j];
            c[2][j] += xa.z * w[j];
            c[3][j] += xa.w * w[j];
        }
    }
    fx4 bb[4];
    bb[0] = *(const fx4*)&bias[tx * 8];
    bb[1] = *(const fx4*)&bias[tx * 8 + 4];
    bb[2] = *(const fx4*)&bias[tx * 8 + 128];
    bb[3] = *(const fx4*)&bias[tx * 8 + 132];
    #pragma unroll
    for (int i = 0; i < 4; i++) {
        int r = rows0 + ty * 4 + i;
        fx4 v0 = c[i][0] + bb[0], v1 = c[i][1] + bb[1];
        fx4 v2 = c[i][2] + bb[2], v3 = c[i][3] + bb[3];
        hx8 h0, h1;
        #pragma unroll
        for (int q = 0; q < 4; q++) {
            h0[q]     = (_Float16)fmaxf(v0[q], 0.f);
            h0[q + 4] = (_Float16)fmaxf(v1[q], 0.f);
            h1[q]     = (_Float16)fmaxf(v2[q], 0.f);
            h1[q + 4] = (_Float16)fmaxf(v3[q], 0.f);
        }
        *(hx8*)&H[(size_t)r * 256 + tx * 8]       = h0;
        *(hx8*)&H[(size_t)r * 256 + tx * 8 + 128] = h1;
    }
}

// gemm2 MFMA: Z[N,256] = fp16( H[N,256] @ W2 ), 128x128 tile, BK=64, dbuf LDS.
#define LDH 72
__global__ __launch_bounds__(256, 2) void k_gemm2m(const _Float16* __restrict__ A,
                                                   const _Float16* __restrict__ Bt,
                                                   _Float16* __restrict__ Z) {
    __shared__ __align__(16) _Float16 As[2][128 * LDH];
    __shared__ __align__(16) _Float16 Bs[2][128 * LDH];
    int tid = threadIdx.x;
    int lane = tid & 63, wid = tid >> 6;
    int wm = wid >> 1, wn = wid & 1;
    int row0 = blockIdx.x * 128, col0 = blockIdx.y * 128;
    int l15 = lane & 15, g = lane >> 4;
    int sr = tid >> 3, sc = tid & 7;

    fx4 acc[4][4];
    #pragma unroll
    for (int m = 0; m < 4; m++)
        #pragma unroll
        for (int n = 0; n < 4; n++) acc[m][n] = (fx4){0.f, 0.f, 0.f, 0.f};

    uint4 ga[4], gb[4];
    #pragma unroll
    for (int it = 0; it < 4; it++) {
        ga[it] = *(const uint4*)&A[(size_t)(row0 + sr + 32 * it) * 256 + sc * 8];
        gb[it] = *(const uint4*)&Bt[(size_t)(col0 + sr + 32 * it) * 256 + sc * 8];
    }
    #pragma unroll
    for (int it = 0; it < 4; it++) {
        *(uint4*)&As[0][(sr + 32 * it) * LDH + sc * 8] = ga[it];
        *(uint4*)&Bs[0][(sr + 32 * it) * LDH + sc * 8] = gb[it];
    }
    __syncthreads();

    int cur = 0;
    for (int t = 0; t < 4; t++) {
        if (t < 3) {
            int k0 = (t + 1) * 64;
            #pragma unroll
            for (int it = 0; it < 4; it++) {
                ga[it] = *(const uint4*)&A[(size_t)(row0 + sr + 32 * it) * 256 + k0 + sc * 8];
                gb[it] = *(const uint4*)&Bt[(size_t)(col0 + sr + 32 * it) * 256 + k0 + sc * 8];
            }
        }
        const _Float16* ap = As[cur];
        const _Float16* bp = Bs[cur];
        hx8 af[4][2], bf[4][2];
        #pragma unroll
        for (int m = 0; m < 4; m++)
            #pragma unroll
            for (int ks = 0; ks < 2; ks++)
                af[m][ks] = *(const hx8*)&ap[(wm * 64 + m * 16 + l15) * LDH + ks * 32 + g * 8];
        #pragma unroll
        for (int n = 0; n < 4; n++)
            #pragma unroll
            for (int ks = 0; ks < 2; ks++)
                bf[n][ks] = *(const hx8*)&bp[(wn * 64 + n * 16 + l15) * LDH + ks * 32 + g * 8];
        #pragma unroll
        for (int m = 0; m < 4; m++)
            #pragma unroll
            for (int n = 0; n < 4; n++) {
                acc[m][n] = __builtin_amdgcn_mfma_f32_16x16x32_f16(af[m][0], bf[n][0], acc[m][n], 0, 0, 0);
                acc[m][n] = __builtin_amdgcn_mfma_f32_16x16x32_f16(af[m][1], bf[n][1], acc[m][n], 0, 0, 0);
            }
        if (t < 3) {
            #pragma unroll
            for (int it = 0; it < 4; it++) {
                *(uint4*)&As[cur ^ 1][(sr + 32 * it) * LDH + sc * 8] = ga[it];
                *(uint4*)&Bs[cur ^ 1][(sr + 32 * it) * LDH + sc * 8] = gb[it];
            }
        }
        __syncthreads();
        cur ^= 1;
    }

    #pragma unroll
    for (int m = 0; m < 4; m++)
        #pragma unroll
        for (int n = 0; n < 4; n++) {
            int cc = col0 + wn * 64 + n * 16 + l15;
            #pragma unroll
            for (int r = 0; r < 4; r++) {
                int rr = row0 + wm * 64 + m * 16 + g * 4 + r;
                Z[(size_t)rr * 256 + cc] = (_Float16)acc[m][n][r];
            }
        }
}

#define ACC8(v, m) \
    a0.x = fmaf((float)v[0], m, a0.x); a0.y = fmaf((float)v[1], m, a0.y); \
    a0.z = fmaf((float)v[2], m, a0.z); a0.w = fmaf((float)v[3], m, a0.w); \
    a1.x = fmaf((float)v[4], m, a1.x); a1.y = fmaf((float)v[5], m, a1.y); \
    a1.z = fmaf((float)v[6], m, a1.z); a1.w = fmaf((float)v[7], m, a1.w);

// agg2 + mean fused: h2 = relu(sum_e dinv[s]*dinv[n]*Z[s,:] + b2); block
// (4 nodes) LDS-reduces and atomically adds h2/512 into pooled[b,:].
__global__ __launch_bounds__(256) void k_aggm(const _Float16* __restrict__ Z, const int* __restrict__ indptr,
                                              const int* __restrict__ csrc, const float* __restrict__ dinv,
                                              const float* __restrict__ bias, float* __restrict__ pooled) {
    __shared__ float ps[4][256];
    int tid = threadIdx.x;
    int wid = tid >> 6, lane = tid & 63;
    int h = lane >> 5, fl = lane & 31;
    int n = blockIdx.x * 4 + wid;
    int beg = indptr[n];
    int half = (indptr[n + 1] - beg) >> 1;   // multiple of 4 (padded lists)
    float dn = dinv[n];
    const int* cs = csrc + beg + h;
    fx4 a0 = (fx4){0.f, 0.f, 0.f, 0.f};
    fx4 a1 = (fx4){0.f, 0.f, 0.f, 0.f};
    for (int i = 0; i < half; i += 4) {
        int s0 = cs[2 * i], s1 = cs[2 * i + 2], s2 = cs[2 * i + 4], s3 = cs[2 * i + 6];
        float m0 = dinv[s0] * dn, m1 = dinv[s1] * dn, m2 = dinv[s2] * dn, m3 = dinv[s3] * dn;
        hx8 v0 = *(const hx8*)&Z[(size_t)s0 * 256 + fl * 8];
        hx8 v1 = *(const hx8*)&Z[(size_t)s1 * 256 + fl * 8];
        hx8 v2 = *(const hx8*)&Z[(size_t)s2 * 256 + fl * 8];
        hx8 v3 = *(const hx8*)&Z[(size_t)s3 * 256 + fl * 8];
        ACC8(v0, m0)
        ACC8(v1, m1)
        ACC8(v2, m2)
        ACC8(v3, m3)
    }
    a0 += shfl_xor4(a0, 32);
    a1 += shfl_xor4(a1, 32);
    fx4 b0 = *(const fx4*)&bias[fl * 8];
    fx4 b1 = *(const fx4*)&bias[fl * 8 + 4];
    a0 += b0; a1 += b1;
    a0.x = fmaxf(a0.x, 0.f); a0.y = fmaxf(a0.y, 0.f);
    a0.z = fmaxf(a0.z, 0.f); a0.w = fmaxf(a0.w, 0.f);
    a1.x = fmaxf(a1.x, 0.f); a1.y = fmaxf(a1.y, 0.f);
    a1.z = fmaxf(a1.z, 0.f); a1.w = fmaxf(a1.w, 0.f);
    if (h == 0) {
        *(fx4*)&ps[wid][fl * 8]     = a0;
        *(fx4*)&ps[wid][fl * 8 + 4] = a1;
    }
    __syncthreads();
    float s = ps[0][tid] + ps[1][tid] + ps[2][tid] + ps[3][tid];
    atomicAdd(&pooled[(blockIdx.x >> 7) * 256 + tid], s * (1.f / 512.f));
}

__global__ __launch_bounds__(64) void k_cls(const float* __restrict__ pooled, const float* __restrict__ cw,
                                            const float* __restrict__ cb, float* __restrict__ outp) {
    int b = blockIdx.x, lane = threadIdx.x;
    float po[10];
    #pragma unroll
    for (int o = 0; o < 10; o++) po[o] = 0.f;
    #pragma unroll
    for (int m = 0; m < 4; m++) {
        int hh = lane + m * 64;
        float ph = pooled[b * HID + hh];
        #pragma unroll
        for (int o = 0; o < 10; o++) po[o] = fmaf(ph, cw[hh * 10 + o], po[o]);
    }
    #pragma unroll
    for (int off = 32; off >= 1; off >>= 1) {
        #pragma unroll
        for (int o = 0; o < 10; o++) po[o] += __shfl_down(po[o], off);
    }
    if (lane == 0) {
        #pragma unroll
        for (int o = 0; o < 10; o++) outp[b * 10 + o] = po[o] + cb[o];
    }
}

extern "C" void kernel_launch(void* const* d_in, const int* in_sizes, int n_in,
                              void* d_out, int out_size, void* d_ws, size_t ws_size,
                              hipStream_t stream) {
    const float* x   = (const float*)d_in[0];
    const int*   ei  = (const int*)d_in[1];
    const float* w1  = (const float*)d_in[2];
    const float* b1  = (const float*)d_in[3];
    const float* w2  = (const float*)d_in[4];
    const float* b2  = (const float*)d_in[5];
    const float* g1w = (const float*)d_in[6];
    const float* g1b = (const float*)d_in[7];
    const float* g2w = (const float*)d_in[8];
    const float* g2b = (const float*)d_in[9];
    const float* cw  = (const float*)d_in[10];
    const float* cb  = (const float*)d_in[11];
    float* out = (float*)d_out;
    char* ws = (char*)d_ws;

    _Float16*       H      = (_Float16*)(ws + OFF_H);
    _Float16*       Z      = (_Float16*)(ws + OFF_Z);
    float*          h1     = (float*)(ws + OFF_H1);
    float*          xn     = (float*)(ws + OFF_XN);
    float*          y1     = (float*)(ws + OFF_Y1);
    int*            deg    = (int*)(ws + OFF_DEG);
    int*            indptr = (int*)(ws + OFF_INDPTR);
    int*            cnt    = (int*)(ws + OFF_CNT);
    float*          dinv   = (float*)(ws + OFF_DINV);
    int*            csrc   = (int*)(ws + OFF_CSRC);
    float*          wt1    = (float*)(ws + OFF_WT1);
    float*          wt2    = (float*)(ws + OFF_WT2);
    float*          pooled = (float*)(ws + OFF_POOL);
    _Float16*       w2t    = (_Float16*)(ws + OFF_W2T);
    float*          xnz    = xn + (size_t)NN * 32;          // dummy row NN of xn
    unsigned*       zz     = (unsigned*)(Z + (size_t)NN * 256);  // dummy row NN of Z

    k_setup<<<174, 256, 0, stream>>>(deg, cnt, pooled, w1, w2, wt1, wt2, g2w, w2t, xnz, zz);
    k_count<<<2048, 256, 0, stream>>>(ei, deg);
    k_conv1<<<dim3(8, 64), 256, 0, stream>>>(x, wt1, b1, h1);
    k_scan <<<1, 1024, 0, stream>>>(deg, indptr, dinv);
    k_fill <<<2304, 256, 0, stream>>>(ei, deg, indptr, cnt, csrc);
    k_conv2<<<dim3(4, 64), 256, 0, stream>>>(h1, wt2, b2, xn);
    k_agg32<<<8192, 256, 0, stream>>>(xn, indptr, csrc, dinv, y1);           // y1 = A^ . X (32-wide)
    k_gemm1<<<512, 256, 0, stream>>>(y1, g1w, g1b, H);                       // H = fp16(relu(y1@W1+b1))
    k_gemm2m<<<dim3(256, 2), 256, 0, stream>>>(H, w2t, Z);                   // Z = fp16(H@W2)
    k_aggm <<<8192, 256, 0, stream>>>(Z, indptr, csrc, dinv, g2b, pooled);   // pooled += relu(A^ . Z + b2)/512
    k_cls  <<<64, 64, 0, stream>>>(pooled, cw, cb, out);
}